// Round 2
// baseline (975.440 us; speedup 1.0000x reference)
//
#include <hip/hip_runtime.h>
#include <math.h>

#define LN_EPS 1e-5f

// N=512, L=256, P=64
// ws layout (floats):
//   stats  (float2 per pair-row)   @ 0        524288
//   maskf                          @ 524288   512
//   ILV    [512][256]              @ 524800   131072   (lv/rg interleaved per j)
//   LGRV   [512][256]              @ 655872   131072   (lg/rv interleaved per i)
//   left   [512][128]              @ 786944   65536
//   right  [512][128]              @ 852480   65536
//   Aw     [512][64]               @ 918016   32768
//   Bw     [512][64]               @ 950784   32768
//   Cw     [512][512]              @ 983552   262144
//   sums   (sumL ssL sumR ssR)     @ 1245696  2048
//   cs     (cs0[64] cs1[64])       @ 1247744  128

__device__ __forceinline__ float gelu_f(float x) {
    float x3 = x * x * x;
    float t = 0.7978845608028654f * (x + 0.044715f * x3);
    float e = __expf(2.f * t);
    float th = 1.f - 2.f / (e + 1.f);
    return 0.5f * x * (1.f + th);
}

// ---------- kS: per-pair-row LN stats (mu, rsqrt(var+eps)) + maskf ----------
__global__ __launch_bounds__(256) void kS(const float* __restrict__ pair,
                                          const int* __restrict__ mask,
                                          float2* __restrict__ stats,
                                          float* __restrict__ maskf) {
    const int t = threadIdx.x;
    const int lane = t & 63, w = t >> 6;
    const int r0 = blockIdx.x * 256 + w * 64;
    const int rsub = lane >> 4, f4 = lane & 15;
    for (int it = 0; it < 16; ++it) {
        int r = r0 + it * 4 + rsub;
        float4 v = ((const float4*)pair)[r * 16 + f4];
        float s = v.x + v.y + v.z + v.w;
        float ss = v.x * v.x + v.y * v.y + v.z * v.z + v.w * v.w;
        s += __shfl_xor(s, 1); ss += __shfl_xor(ss, 1);
        s += __shfl_xor(s, 2); ss += __shfl_xor(ss, 2);
        s += __shfl_xor(s, 4); ss += __shfl_xor(ss, 4);
        s += __shfl_xor(s, 8); ss += __shfl_xor(ss, 8);
        if (f4 == 0) {
            float mu = s * (1.f / 64.f);
            float var = ss * (1.f / 64.f) - mu * mu;
            stats[r] = make_float2(mu, rsqrtf(var + LN_EPS));
        }
    }
    if (blockIdx.x == 0) {
        maskf[t] = (float)mask[t];
        maskf[t + 256] = (float)mask[t + 256];
    }
}

// ---------- kA: l = LN(local); write interleaved projection tables ----------
__global__ void kA(const float* __restrict__ loc,
                   const float* __restrict__ Wlg, const float* __restrict__ Wlv,
                   const float* __restrict__ Wrg, const float* __restrict__ Wrv,
                   float* __restrict__ ILV, float* __restrict__ LGRV) {
    const int t = threadIdx.x;
    const int i = blockIdx.x;
    __shared__ float ln_sh[256];
    __shared__ float stats_sh[2];
    if (t < 64) {
        float4 v = ((const float4*)(loc + i * 256))[t];
        float s = v.x + v.y + v.z + v.w;
        float ss = v.x * v.x + v.y * v.y + v.z * v.z + v.w * v.w;
#pragma unroll
        for (int off = 1; off < 64; off <<= 1) {
            s += __shfl_xor(s, off);
            ss += __shfl_xor(ss, off);
        }
        if (t == 0) {
            float mu = s * (1.f / 256.f);
            float var = ss * (1.f / 256.f) - mu * mu;
            stats_sh[0] = mu;
            stats_sh[1] = rsqrtf(var + LN_EPS);
        }
    }
    __syncthreads();
    float mu = stats_sh[0], rs = stats_sh[1];
    ln_sh[t] = (loc[i * 256 + t] - mu) * rs;
    __syncthreads();
#pragma unroll
    for (int h = 0; h < 2; ++h) {
        int o = t + h * 256;
        int mat = o >> 7, n = o & 127;
        const float* W = (mat == 0) ? Wlg : (mat == 1) ? Wlv : (mat == 2) ? Wrg : Wrv;
        float r0 = 0.f, r1 = 0.f, r2 = 0.f, r3 = 0.f;
#pragma unroll
        for (int k = 0; k < 256; k += 4) {
            r0 += ln_sh[k] * W[k * 128 + n];
            r1 += ln_sh[k + 1] * W[(k + 1) * 128 + n];
            r2 += ln_sh[k + 2] * W[(k + 2) * 128 + n];
            r3 += ln_sh[k + 3] * W[(k + 3) * 128 + n];
        }
        float acc = (r0 + r1) + (r2 + r3);
        if (mat == 0) LGRV[i * 256 + 2 * n] = acc;          // lg
        else if (mat == 1) ILV[i * 256 + 2 * n] = acc;      // lv
        else if (mat == 2) ILV[i * 256 + 2 * n + 1] = acc;  // rg
        else LGRV[i * 256 + 2 * n + 1] = acc;               // rv
    }
}

// ---------- kB: fused p-LN (folded) + dual projection + gelu-gate + reductions ----------
// 256 threads: mat = t&1 (0=gate/Wg, 1=value/Wv), n = t>>1 (0..127).
// Weight column in 64 VGPRs. x row via wave-uniform loads (SGPR operand FMAs).
// No LDS at all.
#define TI 16
#define TJ 16
__global__ __launch_bounds__(256, 3) void kB(
    const float* __restrict__ pair, const float2* __restrict__ stats,
    const float* __restrict__ maskf,
    const float* __restrict__ Wg, const float* __restrict__ Wv,
    const float* __restrict__ ILV, const float* __restrict__ LGRV,
    float* __restrict__ left, float* __restrict__ right) {
    const int t = threadIdx.x;
    const int mat = t & 1;
    const int n = t >> 1;
    const int i0 = blockIdx.x * TI;
    const int j0 = blockIdx.y * TJ;

    const float* W = mat ? Wv : Wg;
    float w[64];
    float cs = 0.f;
#pragma unroll
    for (int k = 0; k < 64; ++k) { w[k] = W[k * 128 + n]; cs += w[k]; }

    float lgrv[TI];
#pragma unroll
    for (int ii = 0; ii < TI; ++ii) lgrv[ii] = LGRV[(i0 + ii) * 256 + t];
    float lacc[TI];
#pragma unroll
    for (int ii = 0; ii < TI; ++ii) lacc[ii] = 0.f;

    for (int jj = 0; jj < TJ; ++jj) {
        const int j = j0 + jj;
        const float selv = ILV[j * 256 + t];
        const float mj = maskf[j];          // uniform
        float racc = 0.f;
#pragma unroll
        for (int ii = 0; ii < TI; ++ii) {
            const int i = i0 + ii;
            const float* __restrict__ x = pair + ((size_t)(i * 512 + j)) * 64;  // uniform ptr
            float r0 = 0.f, r1 = 0.f, r2 = 0.f, r3 = 0.f;
#pragma unroll
            for (int k = 0; k < 64; k += 4) {
                r0 += x[k] * w[k];
                r1 += x[k + 1] * w[k + 1];
                r2 += x[k + 2] * w[k + 2];
                r3 += x[k + 3] * w[k + 3];
            }
            float raw = (r0 + r1) + (r2 + r3);
            float2 st = stats[i * 512 + j];  // uniform
            float p = st.y * (raw - st.x * cs);
            float pp = __shfl_xor(p, 1);
            float pg = mat ? pp : p;
            float pv = mat ? p : pp;
            float gb = mat ? selv : lgrv[ii];
            float vb = mat ? lgrv[ii] : selv;
            float resv = gelu_f(gb + pg) * (vb + pv);
            float mi = maskf[i];             // uniform
            lacc[ii] += mj * resv;           // only even lanes' value is ever stored
            racc += mi * resv;               // only odd lanes' value is ever stored
        }
        if (mat) atomicAdd(&right[j * 128 + n], racc * mj);
    }
#pragma unroll
    for (int ii = 0; ii < TI; ++ii)
        if (!mat) atomicAdd(&left[(i0 + ii) * 128 + n], lacc[ii] * maskf[i0 + ii]);
}

// ---------- kD1: row sums/sumsq of left/right, A/B projections, W_out colsums ----------
__global__ void kD1(const float* __restrict__ left, const float* __restrict__ right,
                    const float* __restrict__ W_out,
                    float* __restrict__ Aw, float* __restrict__ Bw,
                    float* __restrict__ sums, float* __restrict__ cs) {
    const int t = threadIdx.x;
    const int r = blockIdx.x;
    const int which = blockIdx.y;
    const float* src = which ? right : left;
    __shared__ float row_sh[128];
    __shared__ float red[4];
    float v = src[r * 128 + t];
    row_sh[t] = v;
    float s = v, ss = v * v;
#pragma unroll
    for (int off = 1; off < 64; off <<= 1) {
        s += __shfl_xor(s, off);
        ss += __shfl_xor(ss, off);
    }
    int wid = t >> 6, lane = t & 63;
    if (lane == 0) { red[wid * 2] = s; red[wid * 2 + 1] = ss; }
    __syncthreads();
    if (t == 0) {
        sums[which * 1024 + r] = red[0] + red[2];
        sums[which * 1024 + 512 + r] = red[1] + red[3];
    }
    if (t < 64) {
        float a = 0.f;
        const float* W2 = W_out + 64 * 64;
#pragma unroll 8
        for (int m = 0; m < 128; ++m) a += row_sh[m] * W2[m * 64 + t];
        (which ? Bw : Aw)[r * 64 + t] = a;
    }
    if (r == 0 && which == 0 && t < 64) {
        float c0 = 0.f, c1 = 0.f;
        for (int k = 0; k < 64; ++k) c0 += W_out[k * 64 + t];
        for (int m = 0; m < 128; ++m) c1 += W_out[(64 + m) * 64 + t];
        cs[t] = c0;
        cs[64 + t] = c1;
    }
}

// ---------- kD2: C = left @ right^T (512x512, K=128) ----------
__global__ void kD2(const float* __restrict__ left, const float* __restrict__ right,
                    float* __restrict__ C) {
    __shared__ float l_sh[32][68];
    __shared__ float r_sh[32][68];
    const int t = threadIdx.x;
    const int tx = t & 15, ty = t >> 4;
    const int i0 = blockIdx.x * 32, j0 = blockIdx.y * 32;
    float acc00 = 0.f, acc01 = 0.f, acc10 = 0.f, acc11 = 0.f;
    for (int kc = 0; kc < 128; kc += 64) {
        __syncthreads();
#pragma unroll
        for (int u = 0; u < 2; ++u) {
            int fi = t + u * 256;
            int row = fi >> 4, kq = (fi & 15) * 4;
            float4 lv4 = *(const float4*)(left + (i0 + row) * 128 + kc + kq);
            float4 rv4 = *(const float4*)(right + (j0 + row) * 128 + kc + kq);
            *(float4*)&l_sh[row][kq] = lv4;
            *(float4*)&r_sh[row][kq] = rv4;
        }
        __syncthreads();
#pragma unroll 8
        for (int k = 0; k < 64; ++k) {
            float l0 = l_sh[ty * 2 + 0][k], l1 = l_sh[ty * 2 + 1][k];
            float r0 = r_sh[tx * 2 + 0][k], r1 = r_sh[tx * 2 + 1][k];
            acc00 += l0 * r0; acc01 += l0 * r1;
            acc10 += l1 * r0; acc11 += l1 * r1;
        }
    }
    C[(size_t)(i0 + ty * 2 + 0) * 512 + j0 + tx * 2 + 0] = acc00;
    C[(size_t)(i0 + ty * 2 + 0) * 512 + j0 + tx * 2 + 1] = acc01;
    C[(size_t)(i0 + ty * 2 + 1) * 512 + j0 + tx * 2 + 0] = acc10;
    C[(size_t)(i0 + ty * 2 + 1) * 512 + j0 + tx * 2 + 1] = acc11;
}

// ---------- kC: out = rs_p*(x@Wo0 - mu_p*cs0) + rs_s*(A[i]+B[j] - mu_s*cs1) ----------
// 256 threads = 4 waves; each wave owns 16 consecutive j of one i. n = lane.
// W_out column in 64 VGPRs; x row via uniform loads; stats from kS. No LDS.
__global__ __launch_bounds__(256) void kC(
    const float* __restrict__ pair, const float2* __restrict__ stats,
    const float* __restrict__ W_out,
    const float* __restrict__ Aw, const float* __restrict__ Bw,
    const float* __restrict__ Cw, const float* __restrict__ sums,
    const float* __restrict__ cs, float* __restrict__ out) {
    const int t = threadIdx.x;
    const int n = t & 63;
    const int wv = t >> 6;
    const int i = blockIdx.x;
    const int j0 = blockIdx.y * 64 + wv * 16;

    float wo[64];
#pragma unroll
    for (int k = 0; k < 64; ++k) wo[k] = W_out[k * 64 + n];

    const float A_in = Aw[i * 64 + n];
    const float sumLi = sums[i], ssLi = sums[512 + i];  // uniform
    const float cs0n = cs[n], cs1n = cs[64 + n];

    for (int jj = 0; jj < 16; ++jj) {
        const int j = j0 + jj;
        const float* __restrict__ x = pair + ((size_t)(i * 512 + j)) * 64;  // uniform
        float r0 = 0.f, r1 = 0.f, r2 = 0.f, r3 = 0.f;
#pragma unroll
        for (int k = 0; k < 64; k += 4) {
            r0 += x[k] * wo[k];
            r1 += x[k + 1] * wo[k + 1];
            r2 += x[k + 2] * wo[k + 2];
            r3 += x[k + 3] * wo[k + 3];
        }
        float raw = (r0 + r1) + (r2 + r3);
        float2 st = stats[i * 512 + j];                 // uniform
        float Bv = Bw[j * 64 + n];
        float Cv = Cw[(size_t)i * 512 + j];             // uniform
        float sumRj = sums[1024 + j], ssRj = sums[1536 + j];  // uniform
        float mu_s = (sumLi + sumRj) * (1.f / 128.f);
        float var_s = (ssLi + 2.f * Cv + ssRj) * (1.f / 128.f) - mu_s * mu_s;
        float rs_s = rsqrtf(var_s + LN_EPS);
        out[((size_t)(i * 512 + j)) * 64 + n] =
            st.y * (raw - st.x * cs0n) + rs_s * (A_in + Bv - mu_s * cs1n);
    }
}

extern "C" void kernel_launch(void* const* d_in, const int* in_sizes, int n_in,
                              void* d_out, int out_size, void* d_ws, size_t ws_size,
                              hipStream_t stream) {
    const float* loc  = (const float*)d_in[0];
    const float* pair = (const float*)d_in[1];
    const int*   mask = (const int*)d_in[2];
    const float* Wpg  = (const float*)d_in[3];
    const float* Wpv  = (const float*)d_in[4];
    const float* Wlg  = (const float*)d_in[5];
    const float* Wlv  = (const float*)d_in[6];
    const float* Wrg  = (const float*)d_in[7];
    const float* Wrv  = (const float*)d_in[8];
    const float* Wout = (const float*)d_in[9];
    float* out = (float*)d_out;
    float* ws = (float*)d_ws;

    float2* stats = (float2*)ws;            // 524288 floats
    float* maskf  = ws + 524288;            // 512
    float* ILV    = ws + 524800;            // 131072
    float* LGRV   = ws + 655872;            // 131072
    float* left   = ws + 786944;            // 65536
    float* right  = ws + 852480;            // 65536
    float* Aw     = ws + 918016;            // 32768
    float* Bw     = ws + 950784;            // 32768
    float* Cw     = ws + 983552;            // 262144
    float* sums   = ws + 1245696;           // 2048
    float* cs     = ws + 1247744;           // 128

    hipMemsetAsync(left, 0, 2 * 65536 * sizeof(float), stream);  // left+right

    kS<<<1024, 256, 0, stream>>>(pair, mask, stats, maskf);
    kA<<<512, 256, 0, stream>>>(loc, Wlg, Wlv, Wrg, Wrv, ILV, LGRV);
    kB<<<dim3(512 / TI, 512 / TJ), 256, 0, stream>>>(pair, stats, maskf, Wpg, Wpv,
                                                     ILV, LGRV, left, right);
    kD1<<<dim3(512, 2), 128, 0, stream>>>(left, right, Wout, Aw, Bw, sums, cs);
    kD2<<<dim3(16, 16), 256, 0, stream>>>(left, right, Cw);
    kC<<<dim3(512, 8), 256, 0, stream>>>(pair, stats, Wout, Aw, Bw, Cw, sums, cs, out);
}

// Round 3
// 655.837 us; speedup vs baseline: 1.4873x; 1.4873x over previous
//
#include <hip/hip_runtime.h>
#include <math.h>

#define LN_EPS 1e-5f

// N=512, L=256, P=64
// ws layout (floats):
//   lg    @ 0        65536     (512x128)
//   lv    @ 65536    65536
//   rg    @ 131072   65536
//   rv    @ 196608   65536
//   left  @ 262144   65536
//   right @ 327680   65536
//   Aw    @ 393216   32768     (512x64)
//   Bw    @ 425984   32768
//   Cw    @ 458752   262144    (512x512)
//   sums  @ 720896   2048      (sumL ssL sumR ssR)
//   cs    @ 722944   128       (cs0[64] cs1[64])

typedef __bf16 bf16x8 __attribute__((ext_vector_type(8)));
typedef float f32x16 __attribute__((ext_vector_type(16)));

__device__ __forceinline__ float gelu_f(float x) {
    float x3 = x * x * x;
    float t = 0.7978845608028654f * (x + 0.044715f * x3);
    float e = __expf(2.f * t);
    float th = 1.f - 2.f / (e + 1.f);
    return 0.5f * x * (1.f + th);
}

// ---------- kA: l = LN(local); lg/lv/rg/rv = l @ W_* (round-1 proven) ----------
__global__ void kA(const float* __restrict__ loc,
                   const float* __restrict__ Wlg, const float* __restrict__ Wlv,
                   const float* __restrict__ Wrg, const float* __restrict__ Wrv,
                   float* __restrict__ proj) {
    const int t = threadIdx.x;
    const int i = blockIdx.x;
    __shared__ float ln_sh[256];
    __shared__ float stats_sh[2];
    if (t < 64) {
        float4 v = ((const float4*)(loc + i * 256))[t];
        float s = v.x + v.y + v.z + v.w;
        float ss = v.x * v.x + v.y * v.y + v.z * v.z + v.w * v.w;
#pragma unroll
        for (int off = 1; off < 64; off <<= 1) {
            s += __shfl_xor(s, off);
            ss += __shfl_xor(ss, off);
        }
        if (t == 0) {
            float mu = s * (1.f / 256.f);
            float var = ss * (1.f / 256.f) - mu * mu;
            stats_sh[0] = mu;
            stats_sh[1] = rsqrtf(var + LN_EPS);
        }
    }
    __syncthreads();
    float mu = stats_sh[0], rs = stats_sh[1];
    ln_sh[t] = (loc[i * 256 + t] - mu) * rs;
    __syncthreads();
#pragma unroll
    for (int h = 0; h < 2; ++h) {
        int o = t + h * 256;
        int mat = o >> 7, n = o & 127;
        const float* W = (mat == 0) ? Wlg : (mat == 1) ? Wlv : (mat == 2) ? Wrg : Wrv;
        float r0 = 0.f, r1 = 0.f, r2 = 0.f, r3 = 0.f;
#pragma unroll
        for (int k = 0; k < 256; k += 4) {
            r0 += ln_sh[k] * W[k * 128 + n];
            r1 += ln_sh[k + 1] * W[(k + 1) * 128 + n];
            r2 += ln_sh[k + 2] * W[(k + 2) * 128 + n];
            r3 += ln_sh[k + 3] * W[(k + 3) * 128 + n];
        }
        proj[mat * 65536 + i * 128 + n] = (r0 + r1) + (r2 + r3);
    }
}

// ---------- kB: MFMA dual-projection + gelu-gate + left/right reductions ----------
// Block: j-tile 32 x KB_TI i's.  4 waves; wave w owns interleaved output cols
// [w*64, w*64+64) as two 32x32 MFMA N-tiles. Interleave: col 2a = gate(a),
// col 2a+1 = value(a)  -> (pg,pv) in adjacent lanes, one shfl_xor(1).
// A (pair rows) is LN-normalized during staging -> no colsum correction.
#define KB_TI 8
__global__ __launch_bounds__(256, 2) void kB(
    const float* __restrict__ pair, const int* __restrict__ mask,
    const float* __restrict__ Wg, const float* __restrict__ Wv,
    const float* __restrict__ lg, const float* __restrict__ lv,
    const float* __restrict__ rg, const float* __restrict__ rv,
    float* __restrict__ left, float* __restrict__ right) {
    __shared__ __bf16 A_sh[32][72];     // row stride 144 B (16B-aligned)
    __shared__ float lv_sh[32][132];
    __shared__ float rg_sh[32][132];
    __shared__ float mj_sh[32];

    const int t = threadIdx.x;
    const int lane = t & 63;
    const int w = t >> 6;
    const int j0 = blockIdx.x * 32;
    const int i0 = blockIdx.y * KB_TI;
    const int c = lane & 31;
    const int half = lane >> 5;
    const int mbase = 4 * half;

    // B fragments (weights) -> 32 VGPRs, loaded once (L2-resident).
    bf16x8 bfrag[2][4];
#pragma unroll
    for (int tt = 0; tt < 2; ++tt) {
        int C = (2 * w + tt) * 32 + c;
        int n = C >> 1;
        const float* Wsrc = (C & 1) ? Wv : Wg;
#pragma unroll
        for (int kt = 0; kt < 4; ++kt) {
            bf16x8 v;
#pragma unroll
            for (int e = 0; e < 8; ++e)
                v[e] = (__bf16)Wsrc[(kt * 16 + half * 8 + e) * 128 + n];
            bfrag[tt][kt] = v;
        }
    }

    for (int idx = t; idx < 1024; idx += 256) {
        int row = idx >> 5, n4 = (idx & 31) * 4;
        *(float4*)&lv_sh[row][n4] = *(const float4*)(lv + (j0 + row) * 128 + n4);
        *(float4*)&rg_sh[row][n4] = *(const float4*)(rg + (j0 + row) * 128 + n4);
    }
    if (t < 32) mj_sh[t] = (float)mask[j0 + t];
    __syncthreads();

    float mjv[16];
#pragma unroll
    for (int r = 0; r < 16; ++r)
        mjv[r] = mj_sh[mbase + (r & 3) + 8 * (r >> 2)];

    float racc[2][16];
#pragma unroll
    for (int tt = 0; tt < 2; ++tt)
#pragma unroll
        for (int r = 0; r < 16; ++r) racc[tt][r] = 0.f;

    const int evencol = !(c & 1);

    for (int ii = 0; ii < KB_TI; ++ii) {
        const int i = i0 + ii;
        if (mask[i] == 0) continue;        // block-uniform skip: masked i contributes nothing
        __syncthreads();
        {   // stage + normalize A: 8 lanes/row, 8 floats each
            int row = t >> 3;
            int kc = (t & 7) * 8;
            const float* src = pair + ((size_t)i * 512 + j0 + row) * 64 + kc;
            float4 v0 = *(const float4*)src;
            float4 v1 = *(const float4*)(src + 4);
            float s = (v0.x + v0.y) + (v0.z + v0.w) + (v1.x + v1.y) + (v1.z + v1.w);
            float ss = v0.x * v0.x + v0.y * v0.y + v0.z * v0.z + v0.w * v0.w +
                       v1.x * v1.x + v1.y * v1.y + v1.z * v1.z + v1.w * v1.w;
            s += __shfl_xor(s, 1); ss += __shfl_xor(ss, 1);
            s += __shfl_xor(s, 2); ss += __shfl_xor(ss, 2);
            s += __shfl_xor(s, 4); ss += __shfl_xor(ss, 4);
            float mu = s * (1.f / 64.f);
            float rs = rsqrtf(ss * (1.f / 64.f) - mu * mu + LN_EPS);
            bf16x8 o;
            o[0] = (__bf16)((v0.x - mu) * rs); o[1] = (__bf16)((v0.y - mu) * rs);
            o[2] = (__bf16)((v0.z - mu) * rs); o[3] = (__bf16)((v0.w - mu) * rs);
            o[4] = (__bf16)((v1.x - mu) * rs); o[5] = (__bf16)((v1.y - mu) * rs);
            o[6] = (__bf16)((v1.z - mu) * rs); o[7] = (__bf16)((v1.w - mu) * rs);
            *(bf16x8*)&A_sh[row][kc] = o;
        }
        __syncthreads();

        f32x16 acc0 = {}; f32x16 acc1 = {};
#pragma unroll
        for (int kt = 0; kt < 4; ++kt) {
            bf16x8 af = *(const bf16x8*)&A_sh[c][kt * 16 + half * 8];
            acc0 = __builtin_amdgcn_mfma_f32_32x32x16_bf16(af, bfrag[0][kt], acc0, 0, 0, 0);
            acc1 = __builtin_amdgcn_mfma_f32_32x32x16_bf16(af, bfrag[1][kt], acc1, 0, 0, 0);
        }

        // epilogue: even col -> left path, odd col -> right path
#pragma unroll
        for (int tt = 0; tt < 2; ++tt) {
            int n = (((2 * w + tt) * 32) + c) >> 1;
            float lgi = lg[i * 128 + n];
            float rvi = rv[i * 128 + n];
            float lsum = 0.f;
#pragma unroll
            for (int r = 0; r < 16; ++r) {
                int m = mbase + (r & 3) + 8 * (r >> 2);
                float v = tt ? acc1[r] : acc0[r];
                float pp = __shfl_xor(v, 1);
                float lvm = lv_sh[m][n];
                float rgm = rg_sh[m][n];
                float gb = evencol ? lgi : rgm;
                float vb = evencol ? lvm : rvi;
                float pg = evencol ? v : pp;
                float pv = evencol ? pp : v;
                float res = gelu_f(gb + pg) * (vb + pv);
                lsum += res * mjv[r];
                racc[tt][r] += res;
            }
            float tot = lsum + __shfl_xor(lsum, 32);
            if (evencol && lane < 32) atomicAdd(&left[i * 128 + n], tot);
        }
    }

    if (!evencol) {
#pragma unroll
        for (int tt = 0; tt < 2; ++tt) {
            int n = (((2 * w + tt) * 32) + c) >> 1;
#pragma unroll
            for (int r = 0; r < 16; ++r) {
                int m = mbase + (r & 3) + 8 * (r >> 2);
                atomicAdd(&right[(j0 + m) * 128 + n], racc[tt][r] * mjv[r]);
            }
        }
    }
}

// ---------- kD1: row sums/sumsq of left/right, A/B projections, W_out colsums ----------
__global__ void kD1(const float* __restrict__ left, const float* __restrict__ right,
                    const float* __restrict__ W_out,
                    float* __restrict__ Aw, float* __restrict__ Bw,
                    float* __restrict__ sums, float* __restrict__ cs) {
    const int t = threadIdx.x;
    const int r = blockIdx.x;
    const int which = blockIdx.y;
    const float* src = which ? right : left;
    __shared__ float row_sh[128];
    __shared__ float red[4];
    float v = src[r * 128 + t];
    row_sh[t] = v;
    float s = v, ss = v * v;
#pragma unroll
    for (int off = 1; off < 64; off <<= 1) {
        s += __shfl_xor(s, off);
        ss += __shfl_xor(ss, off);
    }
    int wid = t >> 6, lane = t & 63;
    if (lane == 0) { red[wid * 2] = s; red[wid * 2 + 1] = ss; }
    __syncthreads();
    if (t == 0) {
        sums[which * 1024 + r] = red[0] + red[2];
        sums[which * 1024 + 512 + r] = red[1] + red[3];
    }
    if (t < 64) {
        float a = 0.f;
        const float* W2 = W_out + 64 * 64;
#pragma unroll 8
        for (int m = 0; m < 128; ++m) a += row_sh[m] * W2[m * 64 + t];
        (which ? Bw : Aw)[r * 64 + t] = a;
    }
    if (r == 0 && which == 0 && t < 64) {
        float c0 = 0.f, c1 = 0.f;
        for (int k = 0; k < 64; ++k) c0 += W_out[k * 64 + t];
        for (int m = 0; m < 128; ++m) c1 += W_out[(64 + m) * 64 + t];
        cs[t] = c0;
        cs[64 + t] = c1;
    }
}

// ---------- kD2: C = left @ right^T (512x512, K=128) ----------
__global__ void kD2(const float* __restrict__ left, const float* __restrict__ right,
                    float* __restrict__ C) {
    __shared__ float l_sh[32][68];
    __shared__ float r_sh[32][68];
    const int t = threadIdx.x;
    const int tx = t & 15, ty = t >> 4;
    const int i0 = blockIdx.x * 32, j0 = blockIdx.y * 32;
    float acc00 = 0.f, acc01 = 0.f, acc10 = 0.f, acc11 = 0.f;
    for (int kc = 0; kc < 128; kc += 64) {
        __syncthreads();
#pragma unroll
        for (int u = 0; u < 2; ++u) {
            int fi = t + u * 256;
            int row = fi >> 4, kq = (fi & 15) * 4;
            float4 lv4 = *(const float4*)(left + (i0 + row) * 128 + kc + kq);
            float4 rv4 = *(const float4*)(right + (j0 + row) * 128 + kc + kq);
            *(float4*)&l_sh[row][kq] = lv4;
            *(float4*)&r_sh[row][kq] = rv4;
        }
        __syncthreads();
#pragma unroll 8
        for (int k = 0; k < 64; ++k) {
            float l0 = l_sh[ty * 2 + 0][k], l1 = l_sh[ty * 2 + 1][k];
            float r0 = r_sh[tx * 2 + 0][k], r1 = r_sh[tx * 2 + 1][k];
            acc00 += l0 * r0; acc01 += l0 * r1;
            acc10 += l1 * r0; acc11 += l1 * r1;
        }
    }
    C[(size_t)(i0 + ty * 2 + 0) * 512 + j0 + tx * 2 + 0] = acc00;
    C[(size_t)(i0 + ty * 2 + 0) * 512 + j0 + tx * 2 + 1] = acc01;
    C[(size_t)(i0 + ty * 2 + 1) * 512 + j0 + tx * 2 + 0] = acc10;
    C[(size_t)(i0 + ty * 2 + 1) * 512 + j0 + tx * 2 + 1] = acc11;
}

// ---------- kC: MFMA pn@Wo0 + decomposed-LN(ppl)@Wo2 epilogue ----------
// Block: one i x 64 j x 64 n. 4 waves: wave w -> M-tile (w&1), N-tile (w>>1).
__global__ __launch_bounds__(256, 2) void kC(
    const float* __restrict__ pair, const float* __restrict__ Wout,
    const float* __restrict__ Aw, const float* __restrict__ Bw,
    const float* __restrict__ Cw, const float* __restrict__ sums,
    const float* __restrict__ cs, float* __restrict__ out) {
    __shared__ __bf16 A_sh[64][72];
    __shared__ float B_sh[64][68];
    __shared__ float Cv_sh[64];
    __shared__ float sR_sh[64];
    __shared__ float ssR_sh[64];

    const int t = threadIdx.x;
    const int lane = t & 63;
    const int w = t >> 6;
    const int i = blockIdx.x;
    const int j0 = blockIdx.y * 64;
    const int c = lane & 31;
    const int half = lane >> 5;
    const int mt = w & 1;
    const int nt = w >> 1;
    const int n = nt * 32 + c;

    bf16x8 bfrag[4];
#pragma unroll
    for (int kt = 0; kt < 4; ++kt) {
        bf16x8 v;
#pragma unroll
        for (int e = 0; e < 8; ++e)
            v[e] = (__bf16)Wout[(kt * 16 + half * 8 + e) * 64 + n];
        bfrag[kt] = v;
    }

    for (int idx = t; idx < 1024; idx += 256) {
        int row = idx >> 4, n4 = (idx & 15) * 4;
        *(float4*)&B_sh[row][n4] = *(const float4*)(Bw + (j0 + row) * 64 + n4);
    }
    if (t < 64) {
        Cv_sh[t] = Cw[(size_t)i * 512 + j0 + t];
        sR_sh[t] = sums[1024 + j0 + t];
        ssR_sh[t] = sums[1536 + j0 + t];
    }
    {   // stage + normalize A: 4 lanes/row, 16 floats each
        int row = t >> 2;
        int kc = (t & 3) * 16;
        const float* src = pair + ((size_t)i * 512 + j0 + row) * 64 + kc;
        float4 v0 = *(const float4*)src;
        float4 v1 = *(const float4*)(src + 4);
        float4 v2 = *(const float4*)(src + 8);
        float4 v3 = *(const float4*)(src + 12);
        float s = (v0.x + v0.y + v0.z + v0.w) + (v1.x + v1.y + v1.z + v1.w) +
                  (v2.x + v2.y + v2.z + v2.w) + (v3.x + v3.y + v3.z + v3.w);
        float ss = v0.x * v0.x + v0.y * v0.y + v0.z * v0.z + v0.w * v0.w +
                   v1.x * v1.x + v1.y * v1.y + v1.z * v1.z + v1.w * v1.w +
                   v2.x * v2.x + v2.y * v2.y + v2.z * v2.z + v2.w * v2.w +
                   v3.x * v3.x + v3.y * v3.y + v3.z * v3.z + v3.w * v3.w;
        s += __shfl_xor(s, 1); ss += __shfl_xor(ss, 1);
        s += __shfl_xor(s, 2); ss += __shfl_xor(ss, 2);
        float mu = s * (1.f / 64.f);
        float rs = rsqrtf(ss * (1.f / 64.f) - mu * mu + LN_EPS);
        bf16x8 o0, o1;
        o0[0] = (__bf16)((v0.x - mu) * rs); o0[1] = (__bf16)((v0.y - mu) * rs);
        o0[2] = (__bf16)((v0.z - mu) * rs); o0[3] = (__bf16)((v0.w - mu) * rs);
        o0[4] = (__bf16)((v1.x - mu) * rs); o0[5] = (__bf16)((v1.y - mu) * rs);
        o0[6] = (__bf16)((v1.z - mu) * rs); o0[7] = (__bf16)((v1.w - mu) * rs);
        o1[0] = (__bf16)((v2.x - mu) * rs); o1[1] = (__bf16)((v2.y - mu) * rs);
        o1[2] = (__bf16)((v2.z - mu) * rs); o1[3] = (__bf16)((v2.w - mu) * rs);
        o1[4] = (__bf16)((v3.x - mu) * rs); o1[5] = (__bf16)((v3.y - mu) * rs);
        o1[6] = (__bf16)((v3.z - mu) * rs); o1[7] = (__bf16)((v3.w - mu) * rs);
        *(bf16x8*)&A_sh[row][kc] = o0;
        *(bf16x8*)&A_sh[row][kc + 8] = o1;
    }
    __syncthreads();

    f32x16 acc = {};
#pragma unroll
    for (int kt = 0; kt < 4; ++kt) {
        bf16x8 af = *(const bf16x8*)&A_sh[mt * 32 + c][kt * 16 + half * 8];
        acc = __builtin_amdgcn_mfma_f32_32x32x16_bf16(af, bfrag[kt], acc, 0, 0, 0);
    }

    const float sumLi = sums[i], ssLi = sums[512 + i];
    const float A_in = Aw[i * 64 + n];
    const float cs1n = cs[64 + n];

#pragma unroll
    for (int r = 0; r < 16; ++r) {
        int m = mt * 32 + 4 * half + (r & 3) + 8 * (r >> 2);
        float Bv = B_sh[m][n];
        float Cv = Cv_sh[m];
        float mu_s = (sumLi + sR_sh[m]) * (1.f / 128.f);
        float var_s = (ssLi + 2.f * Cv + ssR_sh[m]) * (1.f / 128.f) - mu_s * mu_s;
        float rs_s = rsqrtf(var_s + LN_EPS);
        out[((size_t)i * 512 + j0 + m) * 64 + n] = acc[r] + rs_s * (A_in + Bv - mu_s * cs1n);
    }
}

extern "C" void kernel_launch(void* const* d_in, const int* in_sizes, int n_in,
                              void* d_out, int out_size, void* d_ws, size_t ws_size,
                              hipStream_t stream) {
    const float* loc  = (const float*)d_in[0];
    const float* pair = (const float*)d_in[1];
    const int*   mask = (const int*)d_in[2];
    const float* Wpg  = (const float*)d_in[3];
    const float* Wpv  = (const float*)d_in[4];
    const float* Wlg  = (const float*)d_in[5];
    const float* Wlv  = (const float*)d_in[6];
    const float* Wrg  = (const float*)d_in[7];
    const float* Wrv  = (const float*)d_in[8];
    const float* Wout = (const float*)d_in[9];
    float* out = (float*)d_out;
    float* ws = (float*)d_ws;

    float* proj  = ws;            // lg lv rg rv
    float* left  = ws + 262144;
    float* right = ws + 327680;
    float* Aw    = ws + 393216;
    float* Bw    = ws + 425984;
    float* Cw    = ws + 458752;
    float* sums  = ws + 720896;
    float* cs    = ws + 722944;

    hipMemsetAsync(left, 0, 2 * 65536 * sizeof(float), stream);  // left+right

    kA<<<512, 256, 0, stream>>>(loc, Wlg, Wlv, Wrg, Wrv, proj);
    kB<<<dim3(16, 512 / KB_TI), 256, 0, stream>>>(pair, mask, Wpg, Wpv,
                                                  proj, proj + 65536, proj + 131072,
                                                  proj + 196608, left, right);
    kD1<<<dim3(512, 2), 128, 0, stream>>>(left, right, Wout, Aw, Bw, sums, cs);
    kD2<<<dim3(16, 16), 256, 0, stream>>>(left, right, Cw);
    kC<<<dim3(512, 8), 256, 0, stream>>>(pair, Wout, Aw, Bw, Cw, sums, cs, out);
}

// Round 4
// 228.661 us; speedup vs baseline: 4.2659x; 2.8682x over previous
//
#include <hip/hip_runtime.h>
#include <math.h>

#define LN_EPS 1e-5f

// N=512, L=256, P=64
// ws layout (floats):
//   lg    @ 0        65536     (512x128)
//   lv    @ 65536    65536
//   rg    @ 131072   65536
//   rv    @ 196608   65536
//   left  @ 262144   65536
//   right @ 327680   65536
//   Aw    @ 393216   32768     (512x64)
//   Bw    @ 425984   32768
//   Cw    @ 458752   262144    (512x512)
//   sums  @ 720896   2048      (sumL ssL sumR ssR)
//   cs    @ 722944   128       (cs0[64] cs1[64])

typedef __bf16 bf16x8 __attribute__((ext_vector_type(8)));
typedef float f32x16 __attribute__((ext_vector_type(16)));

__device__ __forceinline__ float gelu_f(float x) {
    float x3 = x * x * x;
    float t = 0.7978845608028654f * (x + 0.044715f * x3);
    float e = __expf(2.f * t);
    float th = 1.f - 2.f / (e + 1.f);
    return 0.5f * x * (1.f + th);
}

// ---------- kA: l = LN(local); proj[mat] = l @ W_mat ----------
// grid (64 i-octets, 4 mats), 256 threads.
// Phase 1: stage 8 LN'd rows (8 KB LDS). Phase 2: thread = (n=t&127, khalf=t>>7),
// 8 row-accumulators; per 4-k chunk: 4 coalesced W loads (batched) + 8 broadcast
// ds_read_b128 + 32 FMA. W slab amortized over 8 rows.
__global__ __launch_bounds__(256) void kA(
    const float* __restrict__ loc,
    const float* __restrict__ Wlg, const float* __restrict__ Wlv,
    const float* __restrict__ Wrg, const float* __restrict__ Wrv,
    float* __restrict__ proj) {
    __shared__ float ln_sh[8][260];   // row stride 1040 B (16B-aligned)
    __shared__ float red_sh[128][9];
    const int t = threadIdx.x;
    const int i0 = blockIdx.x * 8;
    const int mat = blockIdx.y;
    const float* __restrict__ W = (mat == 0) ? Wlg : (mat == 1) ? Wlv
                                 : (mat == 2) ? Wrg : Wrv;
    {   // phase 1: 32 lanes per row, 8 floats each
        int row = t >> 5, l32 = t & 31;
        const float4* src = (const float4*)(loc + (i0 + row) * 256);
        float4 v0 = src[l32 * 2];
        float4 v1 = src[l32 * 2 + 1];
        float s = (v0.x + v0.y) + (v0.z + v0.w) + (v1.x + v1.y) + (v1.z + v1.w);
        float ss = v0.x * v0.x + v0.y * v0.y + v0.z * v0.z + v0.w * v0.w +
                   v1.x * v1.x + v1.y * v1.y + v1.z * v1.z + v1.w * v1.w;
#pragma unroll
        for (int off = 1; off < 32; off <<= 1) {
            s += __shfl_xor(s, off);
            ss += __shfl_xor(ss, off);
        }
        float mu = s * (1.f / 256.f);
        float rs = rsqrtf(ss * (1.f / 256.f) - mu * mu + LN_EPS);
        float4 o0, o1;
        o0.x = (v0.x - mu) * rs; o0.y = (v0.y - mu) * rs;
        o0.z = (v0.z - mu) * rs; o0.w = (v0.w - mu) * rs;
        o1.x = (v1.x - mu) * rs; o1.y = (v1.y - mu) * rs;
        o1.z = (v1.z - mu) * rs; o1.w = (v1.w - mu) * rs;
        *(float4*)&ln_sh[row][l32 * 8] = o0;
        *(float4*)&ln_sh[row][l32 * 8 + 4] = o1;
    }
    __syncthreads();

    const int n = t & 127;
    const int kh = t >> 7;
    float acc[8] = {0.f, 0.f, 0.f, 0.f, 0.f, 0.f, 0.f, 0.f};
#pragma unroll 2
    for (int c = 0; c < 32; ++c) {
        const int kc = kh * 128 + c * 4;
        float w0 = W[(kc + 0) * 128 + n];
        float w1 = W[(kc + 1) * 128 + n];
        float w2 = W[(kc + 2) * 128 + n];
        float w3 = W[(kc + 3) * 128 + n];
#pragma unroll
        for (int r = 0; r < 8; ++r) {
            float4 l4 = *(const float4*)&ln_sh[r][kc];   // broadcast b128
            acc[r] += l4.x * w0 + l4.y * w1 + l4.z * w2 + l4.w * w3;
        }
    }
    if (kh == 1) {
#pragma unroll
        for (int r = 0; r < 8; ++r) red_sh[n][r] = acc[r];
    }
    __syncthreads();
    if (kh == 0) {
#pragma unroll
        for (int r = 0; r < 8; ++r)
            proj[mat * 65536 + (i0 + r) * 128 + n] = acc[r] + red_sh[n][r];
    }
}

// ---------- kB: MFMA dual-projection + gelu-gate + left/right reductions ----------
#define KB_TI 8
__global__ __launch_bounds__(256, 2) void kB(
    const float* __restrict__ pair, const int* __restrict__ mask,
    const float* __restrict__ Wg, const float* __restrict__ Wv,
    const float* __restrict__ lg, const float* __restrict__ lv,
    const float* __restrict__ rg, const float* __restrict__ rv,
    float* __restrict__ left, float* __restrict__ right) {
    __shared__ __bf16 A_sh[32][72];     // row stride 144 B (16B-aligned)
    __shared__ float lv_sh[32][132];
    __shared__ float rg_sh[32][132];
    __shared__ float mj_sh[32];

    const int t = threadIdx.x;
    const int lane = t & 63;
    const int w = t >> 6;
    const int j0 = blockIdx.x * 32;
    const int i0 = blockIdx.y * KB_TI;
    const int c = lane & 31;
    const int half = lane >> 5;
    const int mbase = 4 * half;

    bf16x8 bfrag[2][4];
#pragma unroll
    for (int tt = 0; tt < 2; ++tt) {
        int C = (2 * w + tt) * 32 + c;
        int n = C >> 1;
        const float* Wsrc = (C & 1) ? Wv : Wg;
#pragma unroll
        for (int kt = 0; kt < 4; ++kt) {
            bf16x8 v;
#pragma unroll
            for (int e = 0; e < 8; ++e)
                v[e] = (__bf16)Wsrc[(kt * 16 + half * 8 + e) * 128 + n];
            bfrag[tt][kt] = v;
        }
    }

    for (int idx = t; idx < 1024; idx += 256) {
        int row = idx >> 5, n4 = (idx & 31) * 4;
        *(float4*)&lv_sh[row][n4] = *(const float4*)(lv + (j0 + row) * 128 + n4);
        *(float4*)&rg_sh[row][n4] = *(const float4*)(rg + (j0 + row) * 128 + n4);
    }
    if (t < 32) mj_sh[t] = (float)mask[j0 + t];
    __syncthreads();

    float mjv[16];
#pragma unroll
    for (int r = 0; r < 16; ++r)
        mjv[r] = mj_sh[mbase + (r & 3) + 8 * (r >> 2)];

    float racc[2][16];
#pragma unroll
    for (int tt = 0; tt < 2; ++tt)
#pragma unroll
        for (int r = 0; r < 16; ++r) racc[tt][r] = 0.f;

    const int evencol = !(c & 1);

    for (int ii = 0; ii < KB_TI; ++ii) {
        const int i = i0 + ii;
        if (mask[i] == 0) continue;
        __syncthreads();
        {   // stage + normalize A: 8 lanes/row, 8 floats each
            int row = t >> 3;
            int kc = (t & 7) * 8;
            const float* src = pair + ((size_t)i * 512 + j0 + row) * 64 + kc;
            float4 v0 = *(const float4*)src;
            float4 v1 = *(const float4*)(src + 4);
            float s = (v0.x + v0.y) + (v0.z + v0.w) + (v1.x + v1.y) + (v1.z + v1.w);
            float ss = v0.x * v0.x + v0.y * v0.y + v0.z * v0.z + v0.w * v0.w +
                       v1.x * v1.x + v1.y * v1.y + v1.z * v1.z + v1.w * v1.w;
            s += __shfl_xor(s, 1); ss += __shfl_xor(ss, 1);
            s += __shfl_xor(s, 2); ss += __shfl_xor(ss, 2);
            s += __shfl_xor(s, 4); ss += __shfl_xor(ss, 4);
            float mu = s * (1.f / 64.f);
            float rs = rsqrtf(ss * (1.f / 64.f) - mu * mu + LN_EPS);
            bf16x8 o;
            o[0] = (__bf16)((v0.x - mu) * rs); o[1] = (__bf16)((v0.y - mu) * rs);
            o[2] = (__bf16)((v0.z - mu) * rs); o[3] = (__bf16)((v0.w - mu) * rs);
            o[4] = (__bf16)((v1.x - mu) * rs); o[5] = (__bf16)((v1.y - mu) * rs);
            o[6] = (__bf16)((v1.z - mu) * rs); o[7] = (__bf16)((v1.w - mu) * rs);
            *(bf16x8*)&A_sh[row][kc] = o;
        }
        __syncthreads();

        f32x16 acc0 = {}; f32x16 acc1 = {};
#pragma unroll
        for (int kt = 0; kt < 4; ++kt) {
            bf16x8 af = *(const bf16x8*)&A_sh[c][kt * 16 + half * 8];
            acc0 = __builtin_amdgcn_mfma_f32_32x32x16_bf16(af, bfrag[0][kt], acc0, 0, 0, 0);
            acc1 = __builtin_amdgcn_mfma_f32_32x32x16_bf16(af, bfrag[1][kt], acc1, 0, 0, 0);
        }

#pragma unroll
        for (int tt = 0; tt < 2; ++tt) {
            int n = (((2 * w + tt) * 32) + c) >> 1;
            float lgi = lg[i * 128 + n];
            float rvi = rv[i * 128 + n];
            float lsum = 0.f;
#pragma unroll
            for (int r = 0; r < 16; ++r) {
                int m = mbase + (r & 3) + 8 * (r >> 2);
                float v = tt ? acc1[r] : acc0[r];
                float pp = __shfl_xor(v, 1);
                float lvm = lv_sh[m][n];
                float rgm = rg_sh[m][n];
                float gb = evencol ? lgi : rgm;
                float vb = evencol ? lvm : rvi;
                float pg = evencol ? v : pp;
                float pv = evencol ? pp : v;
                float res = gelu_f(gb + pg) * (vb + pv);
                lsum += res * mjv[r];
                racc[tt][r] += res;
            }
            float tot = lsum + __shfl_xor(lsum, 32);
            if (evencol && lane < 32) atomicAdd(&left[i * 128 + n], tot);
        }
    }

    if (!evencol) {
#pragma unroll
        for (int tt = 0; tt < 2; ++tt) {
            int n = (((2 * w + tt) * 32) + c) >> 1;
#pragma unroll
            for (int r = 0; r < 16; ++r) {
                int m = mbase + (r & 3) + 8 * (r >> 2);
                atomicAdd(&right[(j0 + m) * 128 + n], racc[tt][r] * mjv[r]);
            }
        }
    }
}

// ---------- kD1: row sums/sumsq of left/right, A/B projections, W_out colsums ----------
__global__ void kD1(const float* __restrict__ left, const float* __restrict__ right,
                    const float* __restrict__ W_out,
                    float* __restrict__ Aw, float* __restrict__ Bw,
                    float* __restrict__ sums, float* __restrict__ cs) {
    const int t = threadIdx.x;
    const int r = blockIdx.x;
    const int which = blockIdx.y;
    const float* src = which ? right : left;
    __shared__ float row_sh[128];
    __shared__ float red[4];
    float v = src[r * 128 + t];
    row_sh[t] = v;
    float s = v, ss = v * v;
#pragma unroll
    for (int off = 1; off < 64; off <<= 1) {
        s += __shfl_xor(s, off);
        ss += __shfl_xor(ss, off);
    }
    int wid = t >> 6, lane = t & 63;
    if (lane == 0) { red[wid * 2] = s; red[wid * 2 + 1] = ss; }
    __syncthreads();
    if (t == 0) {
        sums[which * 1024 + r] = red[0] + red[2];
        sums[which * 1024 + 512 + r] = red[1] + red[3];
    }
    if (t < 64) {
        float a = 0.f;
        const float* W2 = W_out + 64 * 64;
#pragma unroll 8
        for (int m = 0; m < 128; ++m) a += row_sh[m] * W2[m * 64 + t];
        (which ? Bw : Aw)[r * 64 + t] = a;
    }
    if (r == 0 && which == 0 && t < 64) {
        float c0 = 0.f, c1 = 0.f;
        for (int k = 0; k < 64; ++k) c0 += W_out[k * 64 + t];
        for (int m = 0; m < 128; ++m) c1 += W_out[(64 + m) * 64 + t];
        cs[t] = c0;
        cs[64 + t] = c1;
    }
}

// ---------- kD2: C = left @ right^T (512x512, K=128) ----------
__global__ void kD2(const float* __restrict__ left, const float* __restrict__ right,
                    float* __restrict__ C) {
    __shared__ float l_sh[32][68];
    __shared__ float r_sh[32][68];
    const int t = threadIdx.x;
    const int tx = t & 15, ty = t >> 4;
    const int i0 = blockIdx.x * 32, j0 = blockIdx.y * 32;
    float acc00 = 0.f, acc01 = 0.f, acc10 = 0.f, acc11 = 0.f;
    for (int kc = 0; kc < 128; kc += 64) {
        __syncthreads();
#pragma unroll
        for (int u = 0; u < 2; ++u) {
            int fi = t + u * 256;
            int row = fi >> 4, kq = (fi & 15) * 4;
            float4 lv4 = *(const float4*)(left + (i0 + row) * 128 + kc + kq);
            float4 rv4 = *(const float4*)(right + (j0 + row) * 128 + kc + kq);
            *(float4*)&l_sh[row][kq] = lv4;
            *(float4*)&r_sh[row][kq] = rv4;
        }
        __syncthreads();
#pragma unroll 8
        for (int k = 0; k < 64; ++k) {
            float l0 = l_sh[ty * 2 + 0][k], l1 = l_sh[ty * 2 + 1][k];
            float r0 = r_sh[tx * 2 + 0][k], r1 = r_sh[tx * 2 + 1][k];
            acc00 += l0 * r0; acc01 += l0 * r1;
            acc10 += l1 * r0; acc11 += l1 * r1;
        }
    }
    C[(size_t)(i0 + ty * 2 + 0) * 512 + j0 + tx * 2 + 0] = acc00;
    C[(size_t)(i0 + ty * 2 + 0) * 512 + j0 + tx * 2 + 1] = acc01;
    C[(size_t)(i0 + ty * 2 + 1) * 512 + j0 + tx * 2 + 0] = acc10;
    C[(size_t)(i0 + ty * 2 + 1) * 512 + j0 + tx * 2 + 1] = acc11;
}

// ---------- kC: MFMA pn@Wo0 + decomposed-LN(ppl)@Wo2 epilogue ----------
__global__ __launch_bounds__(256, 2) void kC(
    const float* __restrict__ pair, const float* __restrict__ Wout,
    const float* __restrict__ Aw, const float* __restrict__ Bw,
    const float* __restrict__ Cw, const float* __restrict__ sums,
    const float* __restrict__ cs, float* __restrict__ out) {
    __shared__ __bf16 A_sh[64][72];
    __shared__ float B_sh[64][68];
    __shared__ float Cv_sh[64];
    __shared__ float sR_sh[64];
    __shared__ float ssR_sh[64];

    const int t = threadIdx.x;
    const int lane = t & 63;
    const int w = t >> 6;
    const int i = blockIdx.x;
    const int j0 = blockIdx.y * 64;
    const int c = lane & 31;
    const int half = lane >> 5;
    const int mt = w & 1;
    const int nt = w >> 1;
    const int n = nt * 32 + c;

    bf16x8 bfrag[4];
#pragma unroll
    for (int kt = 0; kt < 4; ++kt) {
        bf16x8 v;
#pragma unroll
        for (int e = 0; e < 8; ++e)
            v[e] = (__bf16)Wout[(kt * 16 + half * 8 + e) * 64 + n];
        bfrag[kt] = v;
    }

    for (int idx = t; idx < 1024; idx += 256) {
        int row = idx >> 4, n4 = (idx & 15) * 4;
        *(float4*)&B_sh[row][n4] = *(const float4*)(Bw + (j0 + row) * 64 + n4);
    }
    if (t < 64) {
        Cv_sh[t] = Cw[(size_t)i * 512 + j0 + t];
        sR_sh[t] = sums[1024 + j0 + t];
        ssR_sh[t] = sums[1536 + j0 + t];
    }
    {   // stage + normalize A: 4 lanes/row, 16 floats each
        int row = t >> 2;
        int kc = (t & 3) * 16;
        const float* src = pair + ((size_t)i * 512 + j0 + row) * 64 + kc;
        float4 v0 = *(const float4*)src;
        float4 v1 = *(const float4*)(src + 4);
        float4 v2 = *(const float4*)(src + 8);
        float4 v3 = *(const float4*)(src + 12);
        float s = (v0.x + v0.y + v0.z + v0.w) + (v1.x + v1.y + v1.z + v1.w) +
                  (v2.x + v2.y + v2.z + v2.w) + (v3.x + v3.y + v3.z + v3.w);
        float ss = v0.x * v0.x + v0.y * v0.y + v0.z * v0.z + v0.w * v0.w +
                   v1.x * v1.x + v1.y * v1.y + v1.z * v1.z + v1.w * v1.w +
                   v2.x * v2.x + v2.y * v2.y + v2.z * v2.z + v2.w * v2.w +
                   v3.x * v3.x + v3.y * v3.y + v3.z * v3.z + v3.w * v3.w;
        s += __shfl_xor(s, 1); ss += __shfl_xor(ss, 1);
        s += __shfl_xor(s, 2); ss += __shfl_xor(ss, 2);
        float mu = s * (1.f / 64.f);
        float rs = rsqrtf(ss * (1.f / 64.f) - mu * mu + LN_EPS);
        bf16x8 o0, o1;
        o0[0] = (__bf16)((v0.x - mu) * rs); o0[1] = (__bf16)((v0.y - mu) * rs);
        o0[2] = (__bf16)((v0.z - mu) * rs); o0[3] = (__bf16)((v0.w - mu) * rs);
        o0[4] = (__bf16)((v1.x - mu) * rs); o0[5] = (__bf16)((v1.y - mu) * rs);
        o0[6] = (__bf16)((v1.z - mu) * rs); o0[7] = (__bf16)((v1.w - mu) * rs);
        o1[0] = (__bf16)((v2.x - mu) * rs); o1[1] = (__bf16)((v2.y - mu) * rs);
        o1[2] = (__bf16)((v2.z - mu) * rs); o1[3] = (__bf16)((v2.w - mu) * rs);
        o1[4] = (__bf16)((v3.x - mu) * rs); o1[5] = (__bf16)((v3.y - mu) * rs);
        o1[6] = (__bf16)((v3.z - mu) * rs); o1[7] = (__bf16)((v3.w - mu) * rs);
        *(bf16x8*)&A_sh[row][kc] = o0;
        *(bf16x8*)&A_sh[row][kc + 8] = o1;
    }
    __syncthreads();

    f32x16 acc = {};
#pragma unroll
    for (int kt = 0; kt < 4; ++kt) {
        bf16x8 af = *(const bf16x8*)&A_sh[mt * 32 + c][kt * 16 + half * 8];
        acc = __builtin_amdgcn_mfma_f32_32x32x16_bf16(af, bfrag[kt], acc, 0, 0, 0);
    }

    const float sumLi = sums[i], ssLi = sums[512 + i];
    const float A_in = Aw[i * 64 + n];
    const float cs1n = cs[64 + n];

#pragma unroll
    for (int r = 0; r < 16; ++r) {
        int m = mt * 32 + 4 * half + (r & 3) + 8 * (r >> 2);
        float Bv = B_sh[m][n];
        float Cv = Cv_sh[m];
        float mu_s = (sumLi + sR_sh[m]) * (1.f / 128.f);
        float var_s = (ssLi + 2.f * Cv + ssR_sh[m]) * (1.f / 128.f) - mu_s * mu_s;
        float rs_s = rsqrtf(var_s + LN_EPS);
        out[((size_t)i * 512 + j0 + m) * 64 + n] = acc[r] + rs_s * (A_in + Bv - mu_s * cs1n);
    }
}

extern "C" void kernel_launch(void* const* d_in, const int* in_sizes, int n_in,
                              void* d_out, int out_size, void* d_ws, size_t ws_size,
                              hipStream_t stream) {
    const float* loc  = (const float*)d_in[0];
    const float* pair = (const float*)d_in[1];
    const int*   mask = (const int*)d_in[2];
    const float* Wpg  = (const float*)d_in[3];
    const float* Wpv  = (const float*)d_in[4];
    const float* Wlg  = (const float*)d_in[5];
    const float* Wlv  = (const float*)d_in[6];
    const float* Wrg  = (const float*)d_in[7];
    const float* Wrv  = (const float*)d_in[8];
    const float* Wout = (const float*)d_in[9];
    float* out = (float*)d_out;
    float* ws = (float*)d_ws;

    float* proj  = ws;            // lg lv rg rv
    float* left  = ws + 262144;
    float* right = ws + 327680;
    float* Aw    = ws + 393216;
    float* Bw    = ws + 425984;
    float* Cw    = ws + 458752;
    float* sums  = ws + 720896;
    float* cs    = ws + 722944;

    hipMemsetAsync(left, 0, 2 * 65536 * sizeof(float), stream);  // left+right

    kA<<<dim3(64, 4), 256, 0, stream>>>(loc, Wlg, Wlv, Wrg, Wrv, proj);
    kB<<<dim3(16, 512 / KB_TI), 256, 0, stream>>>(pair, mask, Wpg, Wpv,
                                                  proj, proj + 65536, proj + 131072,
                                                  proj + 196608, left, right);
    kD1<<<dim3(512, 2), 128, 0, stream>>>(left, right, Wout, Aw, Bw, sums, cs);
    kD2<<<dim3(16, 16), 256, 0, stream>>>(left, right, Cw);
    kC<<<dim3(512, 8), 256, 0, stream>>>(pair, Wout, Aw, Bw, Cw, sums, cs, out);
}

// Round 5
// 198.668 us; speedup vs baseline: 4.9099x; 1.1510x over previous
//
#include <hip/hip_runtime.h>
#include <math.h>

#define LN_EPS 1e-5f

// N=512, L=256, P=64
// ws layout (floats):
//   proj (lg lv rg rv) @ 0       262144
//   left  @ 262144   65536
//   right @ 327680   65536
//   Aw    @ 393216   32768
//   Bw    @ 425984   32768
//   Cw    @ 458752   262144
//   sums  @ 720896   2048      (sumL ssL sumR ssR)
//   cs    @ 722944   128
//   act   @ 723072   513 ints  (act[0]=count, act[1..] = active indices)

typedef __bf16 bf16x8 __attribute__((ext_vector_type(8)));
typedef float f32x16 __attribute__((ext_vector_type(16)));

__device__ __forceinline__ float gelu_f(float x) {
    // x - x * rcp(exp(2t)+1), 2t*log2e = x*(A + B x^2)
    float x2 = x * x;
    float e = __builtin_amdgcn_exp2f(x * fmaf(0.10294423f, x2, 2.3022079f));
    float r = __builtin_amdgcn_rcpf(e + 1.0f);
    return fmaf(-x, r, x);
}

// ---------- kM: compact active indices ----------
__global__ void kM(const int* __restrict__ mask, int* __restrict__ act) {
    const int t = threadIdx.x;           // 512 threads
    const int lane = t & 63, w = t >> 6;
    __shared__ int wcnt_sh[8];
    int m = (mask[t] != 0);
    unsigned long long b = __ballot(m);
    if (lane == 0) wcnt_sh[w] = __popcll(b);
    __syncthreads();
    int base = 0;
    for (int u = 0; u < w; ++u) base += wcnt_sh[u];
    int pos = base + __popcll(b & ((1ull << lane) - 1ull));
    if (m) act[1 + pos] = t;
    if (t == 511) act[0] = base + __popcll(b);
}

// ---------- kA: l = LN(local); proj[mat] = l @ W_mat (R4-proven) ----------
__global__ __launch_bounds__(256) void kA(
    const float* __restrict__ loc,
    const float* __restrict__ Wlg, const float* __restrict__ Wlv,
    const float* __restrict__ Wrg, const float* __restrict__ Wrv,
    float* __restrict__ proj) {
    __shared__ float ln_sh[8][260];
    __shared__ float red_sh[128][9];
    const int t = threadIdx.x;
    const int i0 = blockIdx.x * 8;
    const int mat = blockIdx.y;
    const float* __restrict__ W = (mat == 0) ? Wlg : (mat == 1) ? Wlv
                                 : (mat == 2) ? Wrg : Wrv;
    {
        int row = t >> 5, l32 = t & 31;
        const float4* src = (const float4*)(loc + (i0 + row) * 256);
        float4 v0 = src[l32 * 2];
        float4 v1 = src[l32 * 2 + 1];
        float s = (v0.x + v0.y) + (v0.z + v0.w) + (v1.x + v1.y) + (v1.z + v1.w);
        float ss = v0.x * v0.x + v0.y * v0.y + v0.z * v0.z + v0.w * v0.w +
                   v1.x * v1.x + v1.y * v1.y + v1.z * v1.z + v1.w * v1.w;
#pragma unroll
        for (int off = 1; off < 32; off <<= 1) {
            s += __shfl_xor(s, off);
            ss += __shfl_xor(ss, off);
        }
        float mu = s * (1.f / 256.f);
        float rs = rsqrtf(ss * (1.f / 256.f) - mu * mu + LN_EPS);
        float4 o0, o1;
        o0.x = (v0.x - mu) * rs; o0.y = (v0.y - mu) * rs;
        o0.z = (v0.z - mu) * rs; o0.w = (v0.w - mu) * rs;
        o1.x = (v1.x - mu) * rs; o1.y = (v1.y - mu) * rs;
        o1.z = (v1.z - mu) * rs; o1.w = (v1.w - mu) * rs;
        *(float4*)&ln_sh[row][l32 * 8] = o0;
        *(float4*)&ln_sh[row][l32 * 8 + 4] = o1;
    }
    __syncthreads();

    const int n = t & 127;
    const int kh = t >> 7;
    float acc[8] = {0.f, 0.f, 0.f, 0.f, 0.f, 0.f, 0.f, 0.f};
#pragma unroll 2
    for (int c = 0; c < 32; ++c) {
        const int kc = kh * 128 + c * 4;
        float w0 = W[(kc + 0) * 128 + n];
        float w1 = W[(kc + 1) * 128 + n];
        float w2 = W[(kc + 2) * 128 + n];
        float w3 = W[(kc + 3) * 128 + n];
#pragma unroll
        for (int r = 0; r < 8; ++r) {
            float4 l4 = *(const float4*)&ln_sh[r][kc];
            acc[r] += l4.x * w0 + l4.y * w1 + l4.z * w2 + l4.w * w3;
        }
    }
    if (kh == 1) {
#pragma unroll
        for (int r = 0; r < 8; ++r) red_sh[n][r] = acc[r];
    }
    __syncthreads();
    if (kh == 0) {
#pragma unroll
        for (int r = 0; r < 8; ++r)
            proj[mat * 65536 + (i0 + r) * 128 + n] = acc[r] + red_sh[n][r];
    }
}

// ---------- kB: compacted i,j; dual-accumulator MFMA; dbuf staging ----------
// 4 waves; wave w owns cols n = w*32 + c (c=lane&31). accg through Wg col n,
// accv through Wv col n -> (pg,pv) same lane, no shfl. j-tile = 32 compacted
// rows; i loop = 8 compacted rows, A double-buffered in LDS.
#define KB_TI 8
__global__ __launch_bounds__(256) void kB(
    const float* __restrict__ pair, const int* __restrict__ act,
    const float* __restrict__ Wg, const float* __restrict__ Wv,
    const float* __restrict__ lg, const float* __restrict__ lv,
    const float* __restrict__ rg, const float* __restrict__ rv,
    float* __restrict__ left, float* __restrict__ right) {
    __shared__ __bf16 A_sh[2][32][72];
    __shared__ float lv_sh[32][132];
    __shared__ float rg_sh[32][132];
    __shared__ int ji_sh[32];
    __shared__ int ii_sh[KB_TI];

    const int cnt = act[0];
    const int j0 = blockIdx.x * 32;
    const int ibase = blockIdx.y * KB_TI;
    if (j0 >= cnt || ibase >= cnt) return;
    const int nact = min(KB_TI, cnt - ibase);

    const int t = threadIdx.x;
    const int lane = t & 63;
    const int w = t >> 6;
    const int c = lane & 31;
    const int half = lane >> 5;
    const int n = w * 32 + c;

    if (t < 32) ji_sh[t] = act[1 + min(j0 + t, cnt - 1)];
    if (t >= 64 && t < 64 + KB_TI) ii_sh[t - 64] = act[1 + min(ibase + (t - 64), cnt - 1)];
    __syncthreads();

    // weight fragments (L2-hot)
    bf16x8 bg[4], bv[4];
#pragma unroll
    for (int kt = 0; kt < 4; ++kt) {
        bf16x8 vg, vv;
#pragma unroll
        for (int e = 0; e < 8; ++e) {
            int kr = kt * 16 + half * 8 + e;
            vg[e] = (__bf16)Wg[kr * 128 + n];
            vv[e] = (__bf16)Wv[kr * 128 + n];
        }
        bg[kt] = vg; bv[kt] = vv;
    }

    // stage lv/rg for the 32 compacted j rows
    for (int idx = t; idx < 32 * 128; idx += 256) {
        int jj = idx >> 7, nn = idx & 127;
        int j = ji_sh[jj];
        lv_sh[jj][nn] = lv[j * 128 + nn];
        rg_sh[jj][nn] = rg[j * 128 + nn];
    }

    const int srow = t >> 3;            // staging row 0..31
    const int kseg = (t & 7) * 8;       // 8 floats per lane
    float4 p0, p1;
    float plg, prv;

    {   // prefetch iter 0
        int iF = act[1 + ibase];
        const float* src = pair + ((size_t)iF * 512 + ji_sh[srow]) * 64 + kseg;
        p0 = *(const float4*)src;
        p1 = *(const float4*)(src + 4);
        plg = lg[iF * 128 + n];
        prv = rv[iF * 128 + n];
    }

    auto lnwrite = [&](int buf) {
        float s = (p0.x + p0.y) + (p0.z + p0.w) + (p1.x + p1.y) + (p1.z + p1.w);
        float ss = p0.x * p0.x + p0.y * p0.y + p0.z * p0.z + p0.w * p0.w +
                   p1.x * p1.x + p1.y * p1.y + p1.z * p1.z + p1.w * p1.w;
        s += __shfl_xor(s, 1); ss += __shfl_xor(ss, 1);
        s += __shfl_xor(s, 2); ss += __shfl_xor(ss, 2);
        s += __shfl_xor(s, 4); ss += __shfl_xor(ss, 4);
        float mu = s * (1.f / 64.f);
        float rs = rsqrtf(ss * (1.f / 64.f) - mu * mu + LN_EPS);
        bf16x8 o;
        o[0] = (__bf16)((p0.x - mu) * rs); o[1] = (__bf16)((p0.y - mu) * rs);
        o[2] = (__bf16)((p0.z - mu) * rs); o[3] = (__bf16)((p0.w - mu) * rs);
        o[4] = (__bf16)((p1.x - mu) * rs); o[5] = (__bf16)((p1.y - mu) * rs);
        o[6] = (__bf16)((p1.z - mu) * rs); o[7] = (__bf16)((p1.w - mu) * rs);
        *(bf16x8*)&A_sh[buf][srow][kseg] = o;
    };
    lnwrite(0);
    __syncthreads();

    float racc[16];
#pragma unroll
    for (int r = 0; r < 16; ++r) racc[r] = 0.f;

    for (int ii = 0; ii < nact; ++ii) {
        const int i = ii_sh[ii];
        const float lgi = plg;
        const float rvi = prv;
        if (ii + 1 < nact) {    // prefetch next i
            int iF = ii_sh[ii + 1];
            const float* src = pair + ((size_t)iF * 512 + ji_sh[srow]) * 64 + kseg;
            p0 = *(const float4*)src;
            p1 = *(const float4*)(src + 4);
            plg = lg[iF * 128 + n];
            prv = rv[iF * 128 + n];
        }

        f32x16 ag = {}; f32x16 av = {};
#pragma unroll
        for (int kt = 0; kt < 4; ++kt) {
            bf16x8 af = *(const bf16x8*)&A_sh[ii & 1][c][kt * 16 + half * 8];
            ag = __builtin_amdgcn_mfma_f32_32x32x16_bf16(af, bg[kt], ag, 0, 0, 0);
            av = __builtin_amdgcn_mfma_f32_32x32x16_bf16(af, bv[kt], av, 0, 0, 0);
        }

        float lsum = 0.f;
#pragma unroll
        for (int r = 0; r < 16; ++r) {
            int m = 4 * half + (r & 3) + 8 * (r >> 2);
            float pg = ag[r], pv = av[r];
            float lres = gelu_f(lgi + pg) * (lv_sh[m][n] + pv);
            float rres = gelu_f(rg_sh[m][n] + pg) * (rvi + pv);
            if (j0 + m < cnt) lsum += lres;
            racc[r] += rres;
        }
        float tot = lsum + __shfl_xor(lsum, 32);
        if (lane < 32) atomicAdd(&left[i * 128 + n], tot);

        if (ii + 1 < nact) lnwrite((ii + 1) & 1);
        __syncthreads();
    }

#pragma unroll
    for (int r = 0; r < 16; ++r) {
        int m = 4 * half + (r & 3) + 8 * (r >> 2);
        if (j0 + m < cnt) atomicAdd(&right[ji_sh[m] * 128 + n], racc[r]);
    }
}

// ---------- kD1: row sums/sumsq of left/right, A/B projections, colsums ----------
__global__ void kD1(const float* __restrict__ left, const float* __restrict__ right,
                    const float* __restrict__ W_out,
                    float* __restrict__ Aw, float* __restrict__ Bw,
                    float* __restrict__ sums, float* __restrict__ cs) {
    const int t = threadIdx.x;
    const int r = blockIdx.x;
    const int which = blockIdx.y;
    const float* src = which ? right : left;
    __shared__ float row_sh[128];
    __shared__ float red[4];
    float v = src[r * 128 + t];
    row_sh[t] = v;
    float s = v, ss = v * v;
#pragma unroll
    for (int off = 1; off < 64; off <<= 1) {
        s += __shfl_xor(s, off);
        ss += __shfl_xor(ss, off);
    }
    int wid = t >> 6, lane = t & 63;
    if (lane == 0) { red[wid * 2] = s; red[wid * 2 + 1] = ss; }
    __syncthreads();
    if (t == 0) {
        sums[which * 1024 + r] = red[0] + red[2];
        sums[which * 1024 + 512 + r] = red[1] + red[3];
    }
    if (t < 64) {
        float a = 0.f;
        const float* W2 = W_out + 64 * 64;
#pragma unroll 8
        for (int m = 0; m < 128; ++m) a += row_sh[m] * W2[m * 64 + t];
        (which ? Bw : Aw)[r * 64 + t] = a;
    }
    if (r == 0 && which == 0 && t < 64) {
        float c0 = 0.f, c1 = 0.f;
        for (int k = 0; k < 64; ++k) c0 += W_out[k * 64 + t];
        for (int m = 0; m < 128; ++m) c1 += W_out[(64 + m) * 64 + t];
        cs[t] = c0;
        cs[64 + t] = c1;
    }
}

// ---------- kD2: C = left @ right^T (512x512, K=128) ----------
__global__ void kD2(const float* __restrict__ left, const float* __restrict__ right,
                    float* __restrict__ C) {
    __shared__ float l_sh[32][68];
    __shared__ float r_sh[32][68];
    const int t = threadIdx.x;
    const int tx = t & 15, ty = t >> 4;
    const int i0 = blockIdx.x * 32, j0 = blockIdx.y * 32;
    float acc00 = 0.f, acc01 = 0.f, acc10 = 0.f, acc11 = 0.f;
    for (int kc = 0; kc < 128; kc += 64) {
        __syncthreads();
#pragma unroll
        for (int u = 0; u < 2; ++u) {
            int fi = t + u * 256;
            int row = fi >> 4, kq = (fi & 15) * 4;
            float4 lv4 = *(const float4*)(left + (i0 + row) * 128 + kc + kq);
            float4 rv4 = *(const float4*)(right + (j0 + row) * 128 + kc + kq);
            *(float4*)&l_sh[row][kq] = lv4;
            *(float4*)&r_sh[row][kq] = rv4;
        }
        __syncthreads();
#pragma unroll 8
        for (int k = 0; k < 64; ++k) {
            float l0 = l_sh[ty * 2 + 0][k], l1 = l_sh[ty * 2 + 1][k];
            float r0 = r_sh[tx * 2 + 0][k], r1 = r_sh[tx * 2 + 1][k];
            acc00 += l0 * r0; acc01 += l0 * r1;
            acc10 += l1 * r0; acc11 += l1 * r1;
        }
    }
    C[(size_t)(i0 + ty * 2 + 0) * 512 + j0 + tx * 2 + 0] = acc00;
    C[(size_t)(i0 + ty * 2 + 0) * 512 + j0 + tx * 2 + 1] = acc01;
    C[(size_t)(i0 + ty * 2 + 1) * 512 + j0 + tx * 2 + 0] = acc10;
    C[(size_t)(i0 + ty * 2 + 1) * 512 + j0 + tx * 2 + 1] = acc11;
}

// ---------- kC: 2 i x 64 j per block; MFMA pn@Wo0 + 3-fma LN epilogue ----------
__global__ __launch_bounds__(256) void kC(
    const float* __restrict__ pair, const float* __restrict__ Wout,
    const float* __restrict__ Aw, const float* __restrict__ Bw,
    const float* __restrict__ Cw, const float* __restrict__ sums,
    const float* __restrict__ cs, float* __restrict__ out) {
    __shared__ __bf16 A_sh[2][64][72];
    __shared__ float rs_sh[128], q_sh[128];

    const int t = threadIdx.x;
    const int lane = t & 63;
    const int w = t >> 6;
    const int c = lane & 31;
    const int half = lane >> 5;
    const int i0 = blockIdx.x * 2;
    const int j0 = blockIdx.y * 64;
    const int isub = w & 1;
    const int nt = w >> 1;
    const int n = nt * 32 + c;
    const int i = i0 + isub;

    bf16x8 bo[4];
#pragma unroll
    for (int kt = 0; kt < 4; ++kt) {
        bf16x8 v;
#pragma unroll
        for (int e = 0; e < 8; ++e)
            v[e] = (__bf16)Wout[(kt * 16 + half * 8 + e) * 64 + n];
        bo[kt] = v;
    }

    if (t < 128) {   // per-(isub, m) secondary-LN stats
        int ip = i0 + (t >> 6);
        int jp = j0 + (t & 63);
        float sumL = sums[ip], ssL = sums[512 + ip];
        float sR = sums[1024 + jp], ssR = sums[1536 + jp];
        float Cv = Cw[(size_t)ip * 512 + jp];
        float mu = (sumL + sR) * (1.f / 128.f);
        float var = (ssL + 2.f * Cv + ssR) * (1.f / 128.f) - mu * mu;
        float rs = rsqrtf(var + LN_EPS);
        rs_sh[t] = rs;
        q_sh[t] = rs * mu;
    }
    {   // stage + LN 128 rows (2 i x 64 j), 2 lanes/row x 32 floats
        int row = t >> 1;
        int kc = (t & 1) * 32;
        const float* src = pair + ((size_t)(i0 + (row >> 6)) * 512 + j0 + (row & 63)) * 64 + kc;
        float4 v[8];
#pragma unroll
        for (int u = 0; u < 8; ++u) v[u] = ((const float4*)src)[u];
        float s = 0.f, ss = 0.f;
#pragma unroll
        for (int u = 0; u < 8; ++u) {
            s += (v[u].x + v[u].y) + (v[u].z + v[u].w);
            ss += v[u].x * v[u].x + v[u].y * v[u].y + v[u].z * v[u].z + v[u].w * v[u].w;
        }
        s += __shfl_xor(s, 1); ss += __shfl_xor(ss, 1);
        float mu = s * (1.f / 64.f);
        float rs = rsqrtf(ss * (1.f / 64.f) - mu * mu + LN_EPS);
#pragma unroll
        for (int u = 0; u < 2; ++u) {
            bf16x8 o;
            o[0] = (__bf16)((v[u*2].x - mu) * rs);   o[1] = (__bf16)((v[u*2].y - mu) * rs);
            o[2] = (__bf16)((v[u*2].z - mu) * rs);   o[3] = (__bf16)((v[u*2].w - mu) * rs);
            o[4] = (__bf16)((v[u*2+1].x - mu) * rs); o[5] = (__bf16)((v[u*2+1].y - mu) * rs);
            o[6] = (__bf16)((v[u*2+1].z - mu) * rs); o[7] = (__bf16)((v[u*2+1].w - mu) * rs);
            *(bf16x8*)&A_sh[row >> 6][row & 63][kc + u * 8] = o;
        }
#pragma unroll
        for (int u = 2; u < 4; ++u) {
            bf16x8 o;
            o[0] = (__bf16)((v[u*2].x - mu) * rs);   o[1] = (__bf16)((v[u*2].y - mu) * rs);
            o[2] = (__bf16)((v[u*2].z - mu) * rs);   o[3] = (__bf16)((v[u*2].w - mu) * rs);
            o[4] = (__bf16)((v[u*2+1].x - mu) * rs); o[5] = (__bf16)((v[u*2+1].y - mu) * rs);
            o[6] = (__bf16)((v[u*2+1].z - mu) * rs); o[7] = (__bf16)((v[u*2+1].w - mu) * rs);
            *(bf16x8*)&A_sh[row >> 6][row & 63][kc + u * 8] = o;
        }
    }
    __syncthreads();

    f32x16 acc0 = {}; f32x16 acc1 = {};
#pragma unroll
    for (int kt = 0; kt < 4; ++kt) {
        bf16x8 a0 = *(const bf16x8*)&A_sh[isub][c][kt * 16 + half * 8];
        bf16x8 a1 = *(const bf16x8*)&A_sh[isub][32 + c][kt * 16 + half * 8];
        acc0 = __builtin_amdgcn_mfma_f32_32x32x16_bf16(a0, bo[kt], acc0, 0, 0, 0);
        acc1 = __builtin_amdgcn_mfma_f32_32x32x16_bf16(a1, bo[kt], acc1, 0, 0, 0);
    }

    const float A_in = Aw[i * 64 + n];
    const float cs1n = cs[64 + n];

#pragma unroll
    for (int mt = 0; mt < 2; ++mt) {
#pragma unroll
        for (int r = 0; r < 16; ++r) {
            int m = mt * 32 + 4 * half + (r & 3) + 8 * (r >> 2);
            float a = mt ? acc1[r] : acc0[r];
            float Bv = Bw[(j0 + m) * 64 + n];
            float rs = rs_sh[isub * 64 + m];
            float q = q_sh[isub * 64 + m];
            out[((size_t)i * 512 + j0 + m) * 64 + n] =
                fmaf(rs, A_in + Bv, fmaf(-q, cs1n, a));
        }
    }
}

extern "C" void kernel_launch(void* const* d_in, const int* in_sizes, int n_in,
                              void* d_out, int out_size, void* d_ws, size_t ws_size,
                              hipStream_t stream) {
    const float* loc  = (const float*)d_in[0];
    const float* pair = (const float*)d_in[1];
    const int*   mask = (const int*)d_in[2];
    const float* Wpg  = (const float*)d_in[3];
    const float* Wpv  = (const float*)d_in[4];
    const float* Wlg  = (const float*)d_in[5];
    const float* Wlv  = (const float*)d_in[6];
    const float* Wrg  = (const float*)d_in[7];
    const float* Wrv  = (const float*)d_in[8];
    const float* Wout = (const float*)d_in[9];
    float* out = (float*)d_out;
    float* ws = (float*)d_ws;

    float* proj  = ws;            // lg lv rg rv
    float* left  = ws + 262144;
    float* right = ws + 327680;
    float* Aw    = ws + 393216;
    float* Bw    = ws + 425984;
    float* Cw    = ws + 458752;
    float* sums  = ws + 720896;
    float* cs    = ws + 722944;
    int*   act   = (int*)(ws + 723072);

    hipMemsetAsync(left, 0, 2 * 65536 * sizeof(float), stream);  // left+right

    kM<<<1, 512, 0, stream>>>(mask, act);
    kA<<<dim3(64, 4), 256, 0, stream>>>(loc, Wlg, Wlv, Wrg, Wrv, proj);
    kB<<<dim3(16, 64), 256, 0, stream>>>(pair, act, Wpg, Wpv,
                                         proj, proj + 65536, proj + 131072,
                                         proj + 196608, left, right);
    kD1<<<dim3(512, 2), 128, 0, stream>>>(left, right, Wout, Aw, Bw, sums, cs);
    kD2<<<dim3(16, 16), 256, 0, stream>>>(left, right, Cw);
    kC<<<dim3(256, 8), 256, 0, stream>>>(pair, Wout, Aw, Bw, Cw, sums, cs, out);
}

// Round 6
// 191.759 us; speedup vs baseline: 5.0868x; 1.0360x over previous
//
#include <hip/hip_runtime.h>
#include <math.h>

#define LN_EPS 1e-5f

// N=512, L=256, P=64
// ws layout (floats):
//   proj (lg lv rg rv) @ 0       262144
//   left  @ 262144   65536
//   right @ 327680   65536
//   Aw    @ 393216   32768
//   Bw    @ 425984   32768
//   Cw    @ 458752   262144
//   sums  @ 720896   2048      (sumL ssL sumR ssR)
//   cs    @ 722944   128
//   act   @ 723072   513 ints  (act[0]=count, act[1..] = active indices)

typedef __bf16 bf16x8 __attribute__((ext_vector_type(8)));
typedef float f32x16 __attribute__((ext_vector_type(16)));

__device__ __forceinline__ float gelu_f(float x) {
    float x2 = x * x;
    float e = __builtin_amdgcn_exp2f(x * fmaf(0.10294423f, x2, 2.3022079f));
    float r = __builtin_amdgcn_rcpf(e + 1.0f);
    return fmaf(-x, r, x);
}

// ---------- kA: LN(local) @ W_*  +  (bx==64): compaction / zero left+right ----------
__global__ __launch_bounds__(256) void kA(
    const float* __restrict__ loc,
    const float* __restrict__ Wlg, const float* __restrict__ Wlv,
    const float* __restrict__ Wrg, const float* __restrict__ Wrv,
    float* __restrict__ proj, const int* __restrict__ mask,
    int* __restrict__ act, float* __restrict__ left, float* __restrict__ right) {
    const int t = threadIdx.x;
    if (blockIdx.x == 64) {
        if (blockIdx.y == 1) {          // zero left
            float4 z = {0.f, 0.f, 0.f, 0.f};
            for (int idx = t; idx < 16384; idx += 256) ((float4*)left)[idx] = z;
        } else if (blockIdx.y == 2) {   // zero right
            float4 z = {0.f, 0.f, 0.f, 0.f};
            for (int idx = t; idx < 16384; idx += 256) ((float4*)right)[idx] = z;
        } else if (blockIdx.y == 0) {   // compact active indices
            __shared__ int cnt_sh[8];
            const int lane = t & 63, wv = t >> 6;
            int msave[2];
            unsigned long long bsave[2];
#pragma unroll
            for (int ch = 0; ch < 2; ++ch) {
                int m = (mask[ch * 256 + t] != 0);
                unsigned long long b = __ballot(m);
                if (lane == 0) cnt_sh[ch * 4 + wv] = __popcll(b);
                msave[ch] = m;
                bsave[ch] = b;
            }
            __syncthreads();
#pragma unroll
            for (int ch = 0; ch < 2; ++ch) {
                int base = 0;
                for (int u = 0; u < ch * 4 + wv; ++u) base += cnt_sh[u];
                int pos = base + __popcll(bsave[ch] & ((1ull << lane) - 1ull));
                if (msave[ch]) act[1 + pos] = ch * 256 + t;
            }
            if (t == 0) {
                int ctot = 0;
                for (int u = 0; u < 8; ++u) ctot += cnt_sh[u];
                act[0] = ctot;
            }
        }
        return;
    }
    __shared__ float ln_sh[8][260];
    __shared__ float red_sh[128][9];
    const int i0 = blockIdx.x * 8;
    const int mat = blockIdx.y;
    const float* __restrict__ W = (mat == 0) ? Wlg : (mat == 1) ? Wlv
                                 : (mat == 2) ? Wrg : Wrv;
    {
        int row = t >> 5, l32 = t & 31;
        const float4* src = (const float4*)(loc + (i0 + row) * 256);
        float4 v0 = src[l32 * 2];
        float4 v1 = src[l32 * 2 + 1];
        float s = (v0.x + v0.y) + (v0.z + v0.w) + (v1.x + v1.y) + (v1.z + v1.w);
        float ss = v0.x * v0.x + v0.y * v0.y + v0.z * v0.z + v0.w * v0.w +
                   v1.x * v1.x + v1.y * v1.y + v1.z * v1.z + v1.w * v1.w;
#pragma unroll
        for (int off = 1; off < 32; off <<= 1) {
            s += __shfl_xor(s, off);
            ss += __shfl_xor(ss, off);
        }
        float mu = s * (1.f / 256.f);
        float rs = rsqrtf(ss * (1.f / 256.f) - mu * mu + LN_EPS);
        float4 o0, o1;
        o0.x = (v0.x - mu) * rs; o0.y = (v0.y - mu) * rs;
        o0.z = (v0.z - mu) * rs; o0.w = (v0.w - mu) * rs;
        o1.x = (v1.x - mu) * rs; o1.y = (v1.y - mu) * rs;
        o1.z = (v1.z - mu) * rs; o1.w = (v1.w - mu) * rs;
        *(float4*)&ln_sh[row][l32 * 8] = o0;
        *(float4*)&ln_sh[row][l32 * 8 + 4] = o1;
    }
    __syncthreads();

    const int n = t & 127;
    const int kh = t >> 7;
    float acc[8] = {0.f, 0.f, 0.f, 0.f, 0.f, 0.f, 0.f, 0.f};
#pragma unroll 2
    for (int c = 0; c < 32; ++c) {
        const int kc = kh * 128 + c * 4;
        float w0 = W[(kc + 0) * 128 + n];
        float w1 = W[(kc + 1) * 128 + n];
        float w2 = W[(kc + 2) * 128 + n];
        float w3 = W[(kc + 3) * 128 + n];
#pragma unroll
        for (int r = 0; r < 8; ++r) {
            float4 l4 = *(const float4*)&ln_sh[r][kc];
            acc[r] += l4.x * w0 + l4.y * w1 + l4.z * w2 + l4.w * w3;
        }
    }
    if (kh == 1) {
#pragma unroll
        for (int r = 0; r < 8; ++r) red_sh[n][r] = acc[r];
    }
    __syncthreads();
    if (kh == 0) {
#pragma unroll
        for (int r = 0; r < 8; ++r)
            proj[mat * 65536 + (i0 + r) * 128 + n] = acc[r] + red_sh[n][r];
    }
}

// ---------- kB: compacted i,j; dual-accumulator MFMA; dbuf staging; reg-resident lv/rg ----------
#define KB_TI 8
__global__ __launch_bounds__(256) void kB(
    const float* __restrict__ pair, const int* __restrict__ act,
    const float* __restrict__ Wg, const float* __restrict__ Wv,
    const float* __restrict__ lg, const float* __restrict__ lv,
    const float* __restrict__ rg, const float* __restrict__ rv,
    float* __restrict__ left, float* __restrict__ right) {
    __shared__ __bf16 A_sh[2][32][72];
    __shared__ int ji_sh[32];
    __shared__ int ii_sh[KB_TI];

    const int cnt = act[0];
    const int j0 = blockIdx.x * 32;
    const int ibase = blockIdx.y * KB_TI;
    if (j0 >= cnt || ibase >= cnt) return;
    const int nact = min(KB_TI, cnt - ibase);

    const int t = threadIdx.x;
    const int lane = t & 63;
    const int w = t >> 6;
    const int c = lane & 31;
    const int half = lane >> 5;
    const int n = w * 32 + c;

    if (t < 32) ji_sh[t] = act[1 + min(j0 + t, cnt - 1)];
    if (t >= 64 && t < 64 + KB_TI) ii_sh[t - 64] = act[1 + min(ibase + (t - 64), cnt - 1)];
    __syncthreads();

    bf16x8 bg[4], bv[4];
#pragma unroll
    for (int kt = 0; kt < 4; ++kt) {
        bf16x8 vg, vv;
#pragma unroll
        for (int e = 0; e < 8; ++e) {
            int kr = kt * 16 + half * 8 + e;
            vg[e] = (__bf16)Wg[kr * 128 + n];
            vv[e] = (__bf16)Wv[kr * 128 + n];
        }
        bg[kt] = vg; bv[kt] = vv;
    }

    // per-lane j-row data for epilogue (j-tile fixed for the whole block)
    float lvr[16], rgr[16];
    unsigned jmask = 0;
#pragma unroll
    for (int r = 0; r < 16; ++r) {
        int m = 4 * half + (r & 3) + 8 * (r >> 2);
        int j = ji_sh[m];
        lvr[r] = lv[j * 128 + n];
        rgr[r] = rg[j * 128 + n];
        if (j0 + m < cnt) jmask |= (1u << r);
    }

    const int srow = t >> 3;
    const int kseg = (t & 7) * 8;
    float4 p0, p1;
    float plg, prv;
    {
        int iF = ii_sh[0];
        const float* src = pair + ((size_t)iF * 512 + ji_sh[srow]) * 64 + kseg;
        p0 = *(const float4*)src;
        p1 = *(const float4*)(src + 4);
        plg = lg[iF * 128 + n];
        prv = rv[iF * 128 + n];
    }

    auto lnwrite = [&](int buf) {
        float s = (p0.x + p0.y) + (p0.z + p0.w) + (p1.x + p1.y) + (p1.z + p1.w);
        float ss = p0.x * p0.x + p0.y * p0.y + p0.z * p0.z + p0.w * p0.w +
                   p1.x * p1.x + p1.y * p1.y + p1.z * p1.z + p1.w * p1.w;
        s += __shfl_xor(s, 1); ss += __shfl_xor(ss, 1);
        s += __shfl_xor(s, 2); ss += __shfl_xor(ss, 2);
        s += __shfl_xor(s, 4); ss += __shfl_xor(ss, 4);
        float mu = s * (1.f / 64.f);
        float rs = rsqrtf(ss * (1.f / 64.f) - mu * mu + LN_EPS);
        bf16x8 o;
        o[0] = (__bf16)((p0.x - mu) * rs); o[1] = (__bf16)((p0.y - mu) * rs);
        o[2] = (__bf16)((p0.z - mu) * rs); o[3] = (__bf16)((p0.w - mu) * rs);
        o[4] = (__bf16)((p1.x - mu) * rs); o[5] = (__bf16)((p1.y - mu) * rs);
        o[6] = (__bf16)((p1.z - mu) * rs); o[7] = (__bf16)((p1.w - mu) * rs);
        *(bf16x8*)&A_sh[buf][srow][kseg] = o;
    };
    lnwrite(0);
    __syncthreads();

    float racc[16];
#pragma unroll
    for (int r = 0; r < 16; ++r) racc[r] = 0.f;

    for (int ii = 0; ii < nact; ++ii) {
        const int i = ii_sh[ii];
        const float lgi = plg;
        const float rvi = prv;
        if (ii + 1 < nact) {
            int iF = ii_sh[ii + 1];
            const float* src = pair + ((size_t)iF * 512 + ji_sh[srow]) * 64 + kseg;
            p0 = *(const float4*)src;
            p1 = *(const float4*)(src + 4);
            plg = lg[iF * 128 + n];
            prv = rv[iF * 128 + n];
        }

        f32x16 ag = {}; f32x16 av = {};
#pragma unroll
        for (int kt = 0; kt < 4; ++kt) {
            bf16x8 af = *(const bf16x8*)&A_sh[ii & 1][c][kt * 16 + half * 8];
            ag = __builtin_amdgcn_mfma_f32_32x32x16_bf16(af, bg[kt], ag, 0, 0, 0);
            av = __builtin_amdgcn_mfma_f32_32x32x16_bf16(af, bv[kt], av, 0, 0, 0);
        }

        float lsum = 0.f;
#pragma unroll
        for (int r = 0; r < 16; ++r) {
            float pg = ag[r], pv = av[r];
            float lres = gelu_f(lgi + pg) * (lvr[r] + pv);
            float rres = gelu_f(rgr[r] + pg) * (rvi + pv);
            lsum += ((jmask >> r) & 1) ? lres : 0.f;
            racc[r] += rres;
        }
        float tot = lsum + __shfl_xor(lsum, 32);
        if (lane < 32) atomicAdd(&left[i * 128 + n], tot);

        if (ii + 1 < nact) lnwrite((ii + 1) & 1);
        __syncthreads();
    }

#pragma unroll
    for (int r = 0; r < 16; ++r) {
        if ((jmask >> r) & 1) {
            int m = 4 * half + (r & 3) + 8 * (r >> 2);
            atomicAdd(&right[ji_sh[m] * 128 + n], racc[r]);
        }
    }
}

// ---------- kD: merged kD1 (row stats + A/B proj + colsums) and kD2 (C = L@R^T) ----------
__global__ __launch_bounds__(256) void kD(
    const float* __restrict__ left, const float* __restrict__ right,
    const float* __restrict__ W_out,
    float* __restrict__ Aw, float* __restrict__ Bw,
    float* __restrict__ sums, float* __restrict__ cs, float* __restrict__ C) {
    const int bx = blockIdx.x;
    const int t = threadIdx.x;
    if (bx < 256) {   // --- kD2 tile ---
        __shared__ float l_sh[32][68];
        __shared__ float r_sh[32][68];
        const int tx = t & 15, ty = t >> 4;
        const int i0 = (bx & 15) * 32, j0 = (bx >> 4) * 32;
        float acc00 = 0.f, acc01 = 0.f, acc10 = 0.f, acc11 = 0.f;
        for (int kc = 0; kc < 128; kc += 64) {
            __syncthreads();
#pragma unroll
            for (int u = 0; u < 2; ++u) {
                int fi = t + u * 256;
                int row = fi >> 4, kq = (fi & 15) * 4;
                float4 lv4 = *(const float4*)(left + (i0 + row) * 128 + kc + kq);
                float4 rv4 = *(const float4*)(right + (j0 + row) * 128 + kc + kq);
                *(float4*)&l_sh[row][kq] = lv4;
                *(float4*)&r_sh[row][kq] = rv4;
            }
            __syncthreads();
#pragma unroll 8
            for (int k = 0; k < 64; ++k) {
                float l0 = l_sh[ty * 2 + 0][k], l1 = l_sh[ty * 2 + 1][k];
                float r0 = r_sh[tx * 2 + 0][k], r1 = r_sh[tx * 2 + 1][k];
                acc00 += l0 * r0; acc01 += l0 * r1;
                acc10 += l1 * r0; acc11 += l1 * r1;
            }
        }
        C[(size_t)(i0 + ty * 2 + 0) * 512 + j0 + tx * 2 + 0] = acc00;
        C[(size_t)(i0 + ty * 2 + 0) * 512 + j0 + tx * 2 + 1] = acc01;
        C[(size_t)(i0 + ty * 2 + 1) * 512 + j0 + tx * 2 + 0] = acc10;
        C[(size_t)(i0 + ty * 2 + 1) * 512 + j0 + tx * 2 + 1] = acc11;
    } else {          // --- kD1: two (r, which) jobs per block ---
        const int id = bx - 256;            // 0..511
        const int which = id >> 8;
        const int sub = t >> 7;
        const int tt = t & 127;
        const int r = (id & 255) * 2 + sub;
        const float* src = which ? right : left;
        __shared__ float row_sh[2][128];
        __shared__ float red[2][4];
        float v = src[r * 128 + tt];
        row_sh[sub][tt] = v;
        float s = v, ss = v * v;
#pragma unroll
        for (int off = 1; off < 64; off <<= 1) {
            s += __shfl_xor(s, off);
            ss += __shfl_xor(ss, off);
        }
        int wid = tt >> 6, lane = tt & 63;
        if (lane == 0) { red[sub][wid * 2] = s; red[sub][wid * 2 + 1] = ss; }
        __syncthreads();
        if (tt == 0) {
            sums[which * 1024 + r] = red[sub][0] + red[sub][2];
            sums[which * 1024 + 512 + r] = red[sub][1] + red[sub][3];
        }
        if (tt < 64) {
            float a = 0.f;
            const float* W2 = W_out + 64 * 64;
#pragma unroll 8
            for (int m = 0; m < 128; ++m) a += row_sh[sub][m] * W2[m * 64 + tt];
            (which ? Bw : Aw)[r * 64 + tt] = a;
        }
        if (id == 0 && t < 64) {
            float c0 = 0.f, c1 = 0.f;
            for (int k = 0; k < 64; ++k) c0 += W_out[k * 64 + t];
            for (int m = 0; m < 128; ++m) c1 += W_out[(64 + m) * 64 + t];
            cs[t] = c0;
            cs[64 + t] = c1;
        }
    }
}

// ---------- kC: barrier-free fragment-direct MFMA + decomposed-LN epilogue ----------
// grid (512, 8), 256 threads = 4 independent waves; wave w: M-tile mt=w&1 (32 j),
// N-tile nt=w>>1 (32 n). A loaded straight into fragment layout from pair;
// LN via one shfl_xor(32). No LDS, no __syncthreads.
__global__ __launch_bounds__(256) void kC(
    const float* __restrict__ pair, const float* __restrict__ Wout,
    const float* __restrict__ Aw, const float* __restrict__ Bw,
    const float* __restrict__ Cw, const float* __restrict__ sums,
    const float* __restrict__ cs, float* __restrict__ out) {
    const int t = threadIdx.x;
    const int lane = t & 63;
    const int w = t >> 6;
    const int c = lane & 31;
    const int half = lane >> 5;
    const int i = blockIdx.x;
    const int j0 = blockIdx.y * 64;
    const int mt = w & 1;
    const int nt = w >> 1;
    const int n = nt * 32 + c;
    const int jrow = j0 + mt * 32 + c;

    const float* __restrict__ asrc = pair + ((size_t)i * 512 + jrow) * 64 + half * 8;
    float4 v[8];
#pragma unroll
    for (int kt = 0; kt < 4; ++kt) {
        v[2 * kt] = *(const float4*)(asrc + kt * 16);
        v[2 * kt + 1] = *(const float4*)(asrc + kt * 16 + 4);
    }
    bf16x8 bo[4];
#pragma unroll
    for (int kt = 0; kt < 4; ++kt) {
        bf16x8 bb;
#pragma unroll
        for (int e = 0; e < 8; ++e)
            bb[e] = (__bf16)Wout[(kt * 16 + half * 8 + e) * 64 + n];
        bo[kt] = bb;
    }
    float s = 0.f, ss = 0.f;
#pragma unroll
    for (int u = 0; u < 8; ++u) {
        s += (v[u].x + v[u].y) + (v[u].z + v[u].w);
        ss += v[u].x * v[u].x + v[u].y * v[u].y + v[u].z * v[u].z + v[u].w * v[u].w;
    }
    s += __shfl_xor(s, 32);
    ss += __shfl_xor(ss, 32);
    float mu = s * (1.f / 64.f);
    float rs = rsqrtf(ss * (1.f / 64.f) - mu * mu + LN_EPS);

    f32x16 acc = {};
#pragma unroll
    for (int kt = 0; kt < 4; ++kt) {
        bf16x8 af;
#pragma unroll
        for (int u = 0; u < 2; ++u) {
            float4 vv = v[2 * kt + u];
            af[u * 4 + 0] = (__bf16)((vv.x - mu) * rs);
            af[u * 4 + 1] = (__bf16)((vv.y - mu) * rs);
            af[u * 4 + 2] = (__bf16)((vv.z - mu) * rs);
            af[u * 4 + 3] = (__bf16)((vv.w - mu) * rs);
        }
        acc = __builtin_amdgcn_mfma_f32_32x32x16_bf16(af, bo[kt], acc, 0, 0, 0);
    }

    const float A_in = Aw[i * 64 + n];
    const float cs1n = cs[64 + n];
    const float sumLi = sums[i], ssLi = sums[512 + i];
#pragma unroll
    for (int r = 0; r < 16; ++r) {
        int jp = j0 + mt * 32 + 4 * half + (r & 3) + 8 * (r >> 2);
        float sR = sums[1024 + jp], ssR = sums[1536 + jp];
        float Cv = Cw[(size_t)i * 512 + jp];
        float Bv = Bw[jp * 64 + n];
        float mu_s = (sumLi + sR) * (1.f / 128.f);
        float var_s = fmaf(-mu_s, mu_s, (ssLi + 2.f * Cv + ssR) * (1.f / 128.f));
        float rs_s = rsqrtf(var_s + LN_EPS);
        out[((size_t)i * 512 + jp) * 64 + n] =
            fmaf(rs_s, (A_in + Bv) - mu_s * cs1n, acc[r]);
    }
}

extern "C" void kernel_launch(void* const* d_in, const int* in_sizes, int n_in,
                              void* d_out, int out_size, void* d_ws, size_t ws_size,
                              hipStream_t stream) {
    const float* loc  = (const float*)d_in[0];
    const float* pair = (const float*)d_in[1];
    const int*   mask = (const int*)d_in[2];
    const float* Wpg  = (const float*)d_in[3];
    const float* Wpv  = (const float*)d_in[4];
    const float* Wlg  = (const float*)d_in[5];
    const float* Wlv  = (const float*)d_in[6];
    const float* Wrg  = (const float*)d_in[7];
    const float* Wrv  = (const float*)d_in[8];
    const float* Wout = (const float*)d_in[9];
    float* out = (float*)d_out;
    float* ws = (float*)d_ws;

    float* proj  = ws;            // lg lv rg rv
    float* left  = ws + 262144;
    float* right = ws + 327680;
    float* Aw    = ws + 393216;
    float* Bw    = ws + 425984;
    float* Cw    = ws + 458752;
    float* sums  = ws + 720896;
    float* cs    = ws + 722944;
    int*   act   = (int*)(ws + 723072);

    kA<<<dim3(65, 4), 256, 0, stream>>>(loc, Wlg, Wlv, Wrg, Wrv, proj,
                                        mask, act, left, right);
    kB<<<dim3(16, 64), 256, 0, stream>>>(pair, act, Wpg, Wpv,
                                         proj, proj + 65536, proj + 131072,
                                         proj + 196608, left, right);
    kD<<<768, 256, 0, stream>>>(left, right, Wout, Aw, Bw, sums, cs, Cw);
    kC<<<dim3(512, 8), 256, 0, stream>>>(pair, Wout, Aw, Bw, Cw, sums, cs, out);
}

// Round 7
// 189.915 us; speedup vs baseline: 5.1362x; 1.0097x over previous
//
#include <hip/hip_runtime.h>
#include <math.h>

#define LN_EPS 1e-5f

// N=512, L=256, P=64
// ws layout (floats):
//   proj (lg lv rg rv) @ 0       262144
//   left  @ 262144   65536
//   right @ 327680   65536
//   Aw    @ 393216   32768
//   Bw    @ 425984   32768
//   Cw    @ 458752   262144
//   sums  @ 720896   2048      (sumL ssL sumR ssR)
//   cs    @ 722944   128
//   act   @ 723072   513 ints  (act[0]=count, act[1..] = active indices)

typedef __bf16 bf16x8 __attribute__((ext_vector_type(8)));
typedef float f32x16 __attribute__((ext_vector_type(16)));

__device__ __forceinline__ float gelu_f(float x) {
    float x2 = x * x;
    float e = __builtin_amdgcn_exp2f(x * fmaf(0.10294423f, x2, 2.3022079f));
    float r = __builtin_amdgcn_rcpf(e + 1.0f);
    return fmaf(-x, r, x);
}

// ---------- kA: LN(local) @ W_*  +  (bx==64): compaction / zero left+right ----------
__global__ __launch_bounds__(256) void kA(
    const float* __restrict__ loc,
    const float* __restrict__ Wlg, const float* __restrict__ Wlv,
    const float* __restrict__ Wrg, const float* __restrict__ Wrv,
    float* __restrict__ proj, const int* __restrict__ mask,
    int* __restrict__ act, float* __restrict__ left, float* __restrict__ right) {
    const int t = threadIdx.x;
    if (blockIdx.x == 64) {
        if (blockIdx.y == 1) {          // zero left
            float4 z = {0.f, 0.f, 0.f, 0.f};
            for (int idx = t; idx < 16384; idx += 256) ((float4*)left)[idx] = z;
        } else if (blockIdx.y == 2) {   // zero right
            float4 z = {0.f, 0.f, 0.f, 0.f};
            for (int idx = t; idx < 16384; idx += 256) ((float4*)right)[idx] = z;
        } else if (blockIdx.y == 0) {   // compact active indices
            __shared__ int cnt_sh[8];
            const int lane = t & 63, wv = t >> 6;
            int msave[2];
            unsigned long long bsave[2];
#pragma unroll
            for (int ch = 0; ch < 2; ++ch) {
                int m = (mask[ch * 256 + t] != 0);
                unsigned long long b = __ballot(m);
                if (lane == 0) cnt_sh[ch * 4 + wv] = __popcll(b);
                msave[ch] = m;
                bsave[ch] = b;
            }
            __syncthreads();
#pragma unroll
            for (int ch = 0; ch < 2; ++ch) {
                int base = 0;
                for (int u = 0; u < ch * 4 + wv; ++u) base += cnt_sh[u];
                int pos = base + __popcll(bsave[ch] & ((1ull << lane) - 1ull));
                if (msave[ch]) act[1 + pos] = ch * 256 + t;
            }
            if (t == 0) {
                int ctot = 0;
                for (int u = 0; u < 8; ++u) ctot += cnt_sh[u];
                act[0] = ctot;
            }
        }
        return;
    }
    __shared__ float ln_sh[8][260];
    __shared__ float red_sh[128][9];
    const int i0 = blockIdx.x * 8;
    const int mat = blockIdx.y;
    const float* __restrict__ W = (mat == 0) ? Wlg : (mat == 1) ? Wlv
                                 : (mat == 2) ? Wrg : Wrv;
    {
        int row = t >> 5, l32 = t & 31;
        const float4* src = (const float4*)(loc + (i0 + row) * 256);
        float4 v0 = src[l32 * 2];
        float4 v1 = src[l32 * 2 + 1];
        float s = (v0.x + v0.y) + (v0.z + v0.w) + (v1.x + v1.y) + (v1.z + v1.w);
        float ss = v0.x * v0.x + v0.y * v0.y + v0.z * v0.z + v0.w * v0.w +
                   v1.x * v1.x + v1.y * v1.y + v1.z * v1.z + v1.w * v1.w;
#pragma unroll
        for (int off = 1; off < 32; off <<= 1) {
            s += __shfl_xor(s, off);
            ss += __shfl_xor(ss, off);
        }
        float mu = s * (1.f / 256.f);
        float rs = rsqrtf(ss * (1.f / 256.f) - mu * mu + LN_EPS);
        float4 o0, o1;
        o0.x = (v0.x - mu) * rs; o0.y = (v0.y - mu) * rs;
        o0.z = (v0.z - mu) * rs; o0.w = (v0.w - mu) * rs;
        o1.x = (v1.x - mu) * rs; o1.y = (v1.y - mu) * rs;
        o1.z = (v1.z - mu) * rs; o1.w = (v1.w - mu) * rs;
        *(float4*)&ln_sh[row][l32 * 8] = o0;
        *(float4*)&ln_sh[row][l32 * 8 + 4] = o1;
    }
    __syncthreads();

    const int n = t & 127;
    const int kh = t >> 7;
    float acc[8] = {0.f, 0.f, 0.f, 0.f, 0.f, 0.f, 0.f, 0.f};
#pragma unroll 2
    for (int c = 0; c < 32; ++c) {
        const int kc = kh * 128 + c * 4;
        float w0 = W[(kc + 0) * 128 + n];
        float w1 = W[(kc + 1) * 128 + n];
        float w2 = W[(kc + 2) * 128 + n];
        float w3 = W[(kc + 3) * 128 + n];
#pragma unroll
        for (int r = 0; r < 8; ++r) {
            float4 l4 = *(const float4*)&ln_sh[r][kc];
            acc[r] += l4.x * w0 + l4.y * w1 + l4.z * w2 + l4.w * w3;
        }
    }
    if (kh == 1) {
#pragma unroll
        for (int r = 0; r < 8; ++r) red_sh[n][r] = acc[r];
    }
    __syncthreads();
    if (kh == 0) {
#pragma unroll
        for (int r = 0; r < 8; ++r)
            proj[mat * 65536 + (i0 + r) * 128 + n] = acc[r] + red_sh[n][r];
    }
}

// ---------- kB: compacted i,j; dual-accumulator MFMA; dbuf staging; reg-resident lv/rg ----------
#define KB_TI 8
__global__ __launch_bounds__(256) void kB(
    const float* __restrict__ pair, const int* __restrict__ act,
    const float* __restrict__ Wg, const float* __restrict__ Wv,
    const float* __restrict__ lg, const float* __restrict__ lv,
    const float* __restrict__ rg, const float* __restrict__ rv,
    float* __restrict__ left, float* __restrict__ right) {
    __shared__ __bf16 A_sh[2][32][72];
    __shared__ int ji_sh[32];
    __shared__ int ii_sh[KB_TI];

    const int cnt = act[0];
    const int j0 = blockIdx.x * 32;
    const int ibase = blockIdx.y * KB_TI;
    if (j0 >= cnt || ibase >= cnt) return;
    const int nact = min(KB_TI, cnt - ibase);

    const int t = threadIdx.x;
    const int lane = t & 63;
    const int w = t >> 6;
    const int c = lane & 31;
    const int half = lane >> 5;
    const int n = w * 32 + c;

    if (t < 32) ji_sh[t] = act[1 + min(j0 + t, cnt - 1)];
    if (t >= 64 && t < 64 + KB_TI) ii_sh[t - 64] = act[1 + min(ibase + (t - 64), cnt - 1)];
    __syncthreads();

    bf16x8 bg[4], bv[4];
#pragma unroll
    for (int kt = 0; kt < 4; ++kt) {
        bf16x8 vg, vv;
#pragma unroll
        for (int e = 0; e < 8; ++e) {
            int kr = kt * 16 + half * 8 + e;
            vg[e] = (__bf16)Wg[kr * 128 + n];
            vv[e] = (__bf16)Wv[kr * 128 + n];
        }
        bg[kt] = vg; bv[kt] = vv;
    }

    float lvr[16], rgr[16];
    unsigned jmask = 0;
#pragma unroll
    for (int r = 0; r < 16; ++r) {
        int m = 4 * half + (r & 3) + 8 * (r >> 2);
        int j = ji_sh[m];
        lvr[r] = lv[j * 128 + n];
        rgr[r] = rg[j * 128 + n];
        if (j0 + m < cnt) jmask |= (1u << r);
    }

    const int srow = t >> 3;
    const int kseg = (t & 7) * 8;
    float4 p0, p1;
    float plg, prv;
    {
        int iF = ii_sh[0];
        const float* src = pair + ((size_t)iF * 512 + ji_sh[srow]) * 64 + kseg;
        p0 = *(const float4*)src;
        p1 = *(const float4*)(src + 4);
        plg = lg[iF * 128 + n];
        prv = rv[iF * 128 + n];
    }

    auto lnwrite = [&](int buf) {
        float s = (p0.x + p0.y) + (p0.z + p0.w) + (p1.x + p1.y) + (p1.z + p1.w);
        float ss = p0.x * p0.x + p0.y * p0.y + p0.z * p0.z + p0.w * p0.w +
                   p1.x * p1.x + p1.y * p1.y + p1.z * p1.z + p1.w * p1.w;
        s += __shfl_xor(s, 1); ss += __shfl_xor(ss, 1);
        s += __shfl_xor(s, 2); ss += __shfl_xor(ss, 2);
        s += __shfl_xor(s, 4); ss += __shfl_xor(ss, 4);
        float mu = s * (1.f / 64.f);
        float rs = rsqrtf(ss * (1.f / 64.f) - mu * mu + LN_EPS);
        bf16x8 o;
        o[0] = (__bf16)((p0.x - mu) * rs); o[1] = (__bf16)((p0.y - mu) * rs);
        o[2] = (__bf16)((p0.z - mu) * rs); o[3] = (__bf16)((p0.w - mu) * rs);
        o[4] = (__bf16)((p1.x - mu) * rs); o[5] = (__bf16)((p1.y - mu) * rs);
        o[6] = (__bf16)((p1.z - mu) * rs); o[7] = (__bf16)((p1.w - mu) * rs);
        *(bf16x8*)&A_sh[buf][srow][kseg] = o;
    };
    lnwrite(0);
    __syncthreads();

    float racc[16];
#pragma unroll
    for (int r = 0; r < 16; ++r) racc[r] = 0.f;

    for (int ii = 0; ii < nact; ++ii) {
        const int i = ii_sh[ii];
        const float lgi = plg;
        const float rvi = prv;
        if (ii + 1 < nact) {
            int iF = ii_sh[ii + 1];
            const float* src = pair + ((size_t)iF * 512 + ji_sh[srow]) * 64 + kseg;
            p0 = *(const float4*)src;
            p1 = *(const float4*)(src + 4);
            plg = lg[iF * 128 + n];
            prv = rv[iF * 128 + n];
        }

        f32x16 ag = {}; f32x16 av = {};
#pragma unroll
        for (int kt = 0; kt < 4; ++kt) {
            bf16x8 af = *(const bf16x8*)&A_sh[ii & 1][c][kt * 16 + half * 8];
            ag = __builtin_amdgcn_mfma_f32_32x32x16_bf16(af, bg[kt], ag, 0, 0, 0);
            av = __builtin_amdgcn_mfma_f32_32x32x16_bf16(af, bv[kt], av, 0, 0, 0);
        }

        float lsum = 0.f;
#pragma unroll
        for (int r = 0; r < 16; ++r) {
            float pg = ag[r], pv = av[r];
            float lres = gelu_f(lgi + pg) * (lvr[r] + pv);
            float rres = gelu_f(rgr[r] + pg) * (rvi + pv);
            lsum += ((jmask >> r) & 1) ? lres : 0.f;
            racc[r] += rres;
        }
        float tot = lsum + __shfl_xor(lsum, 32);
        if (lane < 32) atomicAdd(&left[i * 128 + n], tot);

        if (ii + 1 < nact) lnwrite((ii + 1) & 1);
        __syncthreads();
    }

#pragma unroll
    for (int r = 0; r < 16; ++r) {
        if ((jmask >> r) & 1) {
            int m = 4 * half + (r & 3) + 8 * (r >> 2);
            atomicAdd(&right[ji_sh[m] * 128 + n], racc[r]);
        }
    }
}

// ---------- kD: merged kD1 (row stats + A/B proj + colsums) and kD2 (C = L@R^T) ----------
__global__ __launch_bounds__(256) void kD(
    const float* __restrict__ left, const float* __restrict__ right,
    const float* __restrict__ W_out,
    float* __restrict__ Aw, float* __restrict__ Bw,
    float* __restrict__ sums, float* __restrict__ cs, float* __restrict__ C) {
    const int bx = blockIdx.x;
    const int t = threadIdx.x;
    if (bx < 256) {   // --- kD2 tile ---
        __shared__ float l_sh[32][68];
        __shared__ float r_sh[32][68];
        const int tx = t & 15, ty = t >> 4;
        const int i0 = (bx & 15) * 32, j0 = (bx >> 4) * 32;
        float acc00 = 0.f, acc01 = 0.f, acc10 = 0.f, acc11 = 0.f;
        for (int kc = 0; kc < 128; kc += 64) {
            __syncthreads();
#pragma unroll
            for (int u = 0; u < 2; ++u) {
                int fi = t + u * 256;
                int row = fi >> 4, kq = (fi & 15) * 4;
                float4 lv4 = *(const float4*)(left + (i0 + row) * 128 + kc + kq);
                float4 rv4 = *(const float4*)(right + (j0 + row) * 128 + kc + kq);
                *(float4*)&l_sh[row][kq] = lv4;
                *(float4*)&r_sh[row][kq] = rv4;
            }
            __syncthreads();
#pragma unroll 8
            for (int k = 0; k < 64; ++k) {
                float l0 = l_sh[ty * 2 + 0][k], l1 = l_sh[ty * 2 + 1][k];
                float r0 = r_sh[tx * 2 + 0][k], r1 = r_sh[tx * 2 + 1][k];
                acc00 += l0 * r0; acc01 += l0 * r1;
                acc10 += l1 * r0; acc11 += l1 * r1;
            }
        }
        C[(size_t)(i0 + ty * 2 + 0) * 512 + j0 + tx * 2 + 0] = acc00;
        C[(size_t)(i0 + ty * 2 + 0) * 512 + j0 + tx * 2 + 1] = acc01;
        C[(size_t)(i0 + ty * 2 + 1) * 512 + j0 + tx * 2 + 0] = acc10;
        C[(size_t)(i0 + ty * 2 + 1) * 512 + j0 + tx * 2 + 1] = acc11;
    } else {          // --- kD1: two (r, which) jobs per block ---
        const int id = bx - 256;            // 0..511
        const int which = id >> 8;
        const int sub = t >> 7;
        const int tt = t & 127;
        const int r = (id & 255) * 2 + sub;
        const float* src = which ? right : left;
        __shared__ float row_sh[2][128];
        __shared__ float red[2][4];
        float v = src[r * 128 + tt];
        row_sh[sub][tt] = v;
        float s = v, ss = v * v;
#pragma unroll
        for (int off = 1; off < 64; off <<= 1) {
            s += __shfl_xor(s, off);
            ss += __shfl_xor(ss, off);
        }
        int wid = tt >> 6, lane = tt & 63;
        if (lane == 0) { red[sub][wid * 2] = s; red[sub][wid * 2 + 1] = ss; }
        __syncthreads();
        if (tt == 0) {
            sums[which * 1024 + r] = red[sub][0] + red[sub][2];
            sums[which * 1024 + 512 + r] = red[sub][1] + red[sub][3];
        }
        if (tt < 64) {
            float a = 0.f;
            const float* W2 = W_out + 64 * 64;
#pragma unroll 8
            for (int m = 0; m < 128; ++m) a += row_sh[sub][m] * W2[m * 64 + tt];
            (which ? Bw : Aw)[r * 64 + tt] = a;
        }
        if (id == 0 && t < 64) {
            float c0 = 0.f, c1 = 0.f;
            for (int k = 0; k < 64; ++k) c0 += W_out[k * 64 + t];
            for (int m = 0; m < 128; ++m) c1 += W_out[(64 + m) * 64 + t];
            cs[t] = c0;
            cs[64 + t] = c1;
        }
    }
}

// ---------- kC: 4-deep i-pipelined, barrier-free fragment-direct MFMA ----------
// grid (128, 8); block owns i0..i0+3 x 64 j. 4 independent waves: mt=w&1 (32 j),
// nt=w>>1 (32 n). Pair fragments register-double-buffered: next-i loads issued
// before current-i compute. Wout/Bw hoisted out of the i-loop. No LDS/barriers.
__global__ __launch_bounds__(256) void kC(
    const float* __restrict__ pair, const float* __restrict__ Wout,
    const float* __restrict__ Aw, const float* __restrict__ Bw,
    const float* __restrict__ Cw, const float* __restrict__ sums,
    const float* __restrict__ cs, float* __restrict__ out) {
    const int t = threadIdx.x;
    const int lane = t & 63;
    const int w = t >> 6;
    const int c = lane & 31;
    const int half = lane >> 5;
    const int i0 = blockIdx.x * 4;
    const int j0 = blockIdx.y * 64;
    const int mt = w & 1;
    const int nt = w >> 1;
    const int n = nt * 32 + c;
    const int jrow = j0 + mt * 32 + c;

    const float* __restrict__ abase = pair + ((size_t)i0 * 512 + jrow) * 64 + half * 8;

    float4 va[8], vb[8];
#pragma unroll
    for (int kt = 0; kt < 4; ++kt) {             // issue i0's pair loads first
        va[2 * kt] = *(const float4*)(abase + kt * 16);
        va[2 * kt + 1] = *(const float4*)(abase + kt * 16 + 4);
    }

    bf16x8 bo[4];                                 // i-invariant: Wout fragments
#pragma unroll
    for (int kt = 0; kt < 4; ++kt) {
        bf16x8 bb;
#pragma unroll
        for (int e = 0; e < 8; ++e)
            bb[e] = (__bf16)Wout[(kt * 16 + half * 8 + e) * 64 + n];
        bo[kt] = bb;
    }
    float Bv[16];                                 // i-invariant: Bw values
#pragma unroll
    for (int r = 0; r < 16; ++r) {
        int jp = j0 + mt * 32 + 4 * half + (r & 3) + 8 * (r >> 2);
        Bv[r] = Bw[jp * 64 + n];
    }
    const float cs1n = cs[64 + n];

    auto body = [&](float4 (&cur)[8], float4 (&nxt)[8], int ii) {
        if (ii < 3) {                             // prefetch next i
            const float* src = abase + (size_t)(ii + 1) * 512 * 64;
#pragma unroll
            for (int kt = 0; kt < 4; ++kt) {
                nxt[2 * kt] = *(const float4*)(src + kt * 16);
                nxt[2 * kt + 1] = *(const float4*)(src + kt * 16 + 4);
            }
        }
        const int i = i0 + ii;
        // issue epilogue loads early (complete under MFMA)
        float Cv[16];
#pragma unroll
        for (int r = 0; r < 16; ++r) {
            int jp = j0 + mt * 32 + 4 * half + (r & 3) + 8 * (r >> 2);
            Cv[r] = Cw[(size_t)i * 512 + jp];
        }
        const float A_in = Aw[i * 64 + n];
        const float sumLi = sums[i], ssLi = sums[512 + i];

        float s = 0.f, ss = 0.f;
#pragma unroll
        for (int u = 0; u < 8; ++u) {
            s += (cur[u].x + cur[u].y) + (cur[u].z + cur[u].w);
            ss += cur[u].x * cur[u].x + cur[u].y * cur[u].y +
                  cur[u].z * cur[u].z + cur[u].w * cur[u].w;
        }
        s += __shfl_xor(s, 32);
        ss += __shfl_xor(ss, 32);
        float mu = s * (1.f / 64.f);
        float rs = rsqrtf(ss * (1.f / 64.f) - mu * mu + LN_EPS);

        f32x16 acc = {};
#pragma unroll
        for (int kt = 0; kt < 4; ++kt) {
            bf16x8 af;
#pragma unroll
            for (int u = 0; u < 2; ++u) {
                float4 vv = cur[2 * kt + u];
                af[u * 4 + 0] = (__bf16)((vv.x - mu) * rs);
                af[u * 4 + 1] = (__bf16)((vv.y - mu) * rs);
                af[u * 4 + 2] = (__bf16)((vv.z - mu) * rs);
                af[u * 4 + 3] = (__bf16)((vv.w - mu) * rs);
            }
            acc = __builtin_amdgcn_mfma_f32_32x32x16_bf16(af, bo[kt], acc, 0, 0, 0);
        }

#pragma unroll
        for (int r = 0; r < 16; ++r) {
            int jp = j0 + mt * 32 + 4 * half + (r & 3) + 8 * (r >> 2);
            float sR = sums[1024 + jp], ssR = sums[1536 + jp];
            float mu_s = (sumLi + sR) * (1.f / 128.f);
            float var_s = fmaf(-mu_s, mu_s, (ssLi + 2.f * Cv[r] + ssR) * (1.f / 128.f));
            float rs_s = rsqrtf(var_s + LN_EPS);
            out[((size_t)i * 512 + jp) * 64 + n] =
                fmaf(rs_s, (A_in + Bv[r]) - mu_s * cs1n, acc[r]);
        }
    };
    body(va, vb, 0);
    body(vb, va, 1);
    body(va, vb, 2);
    body(vb, va, 3);
}

extern "C" void kernel_launch(void* const* d_in, const int* in_sizes, int n_in,
                              void* d_out, int out_size, void* d_ws, size_t ws_size,
                              hipStream_t stream) {
    const float* loc  = (const float*)d_in[0];
    const float* pair = (const float*)d_in[1];
    const int*   mask = (const int*)d_in[2];
    const float* Wpg  = (const float*)d_in[3];
    const float* Wpv  = (const float*)d_in[4];
    const float* Wlg  = (const float*)d_in[5];
    const float* Wlv  = (const float*)d_in[6];
    const float* Wrg  = (const float*)d_in[7];
    const float* Wrv  = (const float*)d_in[8];
    const float* Wout = (const float*)d_in[9];
    float* out = (float*)d_out;
    float* ws = (float*)d_ws;

    float* proj  = ws;            // lg lv rg rv
    float* left  = ws + 262144;
    float* right = ws + 327680;
    float* Aw    = ws + 393216;
    float* Bw    = ws + 425984;
    float* Cw    = ws + 458752;
    float* sums  = ws + 720896;
    float* cs    = ws + 722944;
    int*   act   = (int*)(ws + 723072);

    kA<<<dim3(65, 4), 256, 0, stream>>>(loc, Wlg, Wlv, Wrg, Wrv, proj,
                                        mask, act, left, right);
    kB<<<dim3(16, 64), 256, 0, stream>>>(pair, act, Wpg, Wpv,
                                         proj, proj + 65536, proj + 131072,
                                         proj + 196608, left, right);
    kD<<<768, 256, 0, stream>>>(left, right, Wout, Aw, Bw, sums, cs, Cw);
    kC<<<dim3(128, 8), 256, 0, stream>>>(pair, Wout, Aw, Bw, Cw, sums, cs, out);
}